// Round 10
// baseline (375.089 us; speedup 1.0000x reference)
//
#include <hip/hip_runtime.h>
#include <math.h>

#define NB 256
#define NS 64
#define NH 128
#define NZ 128
#define NSTEPS 63
#define HP 144   // HALL row pitch (padh layout within each row)
#define PP 132   // preA/preP/atth(ptrh)/ctx row pitch
#define SP 68    // scores row pitch

// LDS float-offsets (total 39808 floats = 155.5 KiB)
#define OFF_PREA 0       // 8448 (post-chain; WN lives here during startup+chain)
#define OFF_PREP 8448    // 8448 -> [0,16896)
#define OFF_WN   0       // 512*33 = 16896: gate-n weight slices (chain only)
#define OFF_HALL 16896   // 9216 -> [16896,26112)
#define OFF_ATTH 26112   // 8448 -> [26112,34560); post-chain: IH stage, then atth/ptrh
#define OFF_SCOR 34560   // 4352 -> [34560,38912)
#define OFF_U    38912   // 384
#define OFF_VA   39296   // 128
#define OFF_VPV  39424   // 128
#define OFF_REFX 39552   // 64
#define OFF_REFY 39616   // 64
#define OFF_SOL  39680   // 64 (int)
#define OFF_RANK 39744   // 64 (int)
#define SM_FLOATS 39808
// startup temps inside SCOR region (dead before SCOR first written):
#define OFF_GPRE 34560   // 1152
#define OFF_BHH  35712   // 384
#define OFF_AM   36096   // 768
#define OFF_V2   36864   // 384

// +4 pad per 32-float chunk (r1-validated conflict fix for HALL rows)
__device__ __forceinline__ int padh(int i) { return i + ((i >> 5) << 2); }

// fast tanh for the non-recurrent score paths (validated r1/r4-r9)
__device__ __forceinline__ float ftanh(float x) {
  float e = __expf(2.0f * x);
  return 1.0f - 2.0f * __builtin_amdgcn_rcpf(e + 1.0f);
}

// pin 8 scalar floats into VGPRs: asm results can't be rematerialized-by-reload
#define PIN8(a, i)                                                          \
  asm volatile("" : "+v"((a)[(i)]), "+v"((a)[(i) + 1]), "+v"((a)[(i) + 2]), \
                    "+v"((a)[(i) + 3]), "+v"((a)[(i) + 4]),                 \
                    "+v"((a)[(i) + 5]), "+v"((a)[(i) + 6]),                 \
                    "+v"((a)[(i) + 7]))

// ---- pre-kernel: shared fold Wf = (W1[:H] @ W2) @ Wp[H:], computed ONCE ----
__global__ __launch_bounds__(128, 1) void fold_kernel(
    const float* __restrict__ W1, const float* __restrict__ W2,
    const float* __restrict__ Wp, float* __restrict__ gWf) {
  __shared__ float srow[NH];
  const int g = blockIdx.x;   // k-row 0..127
  const int o = threadIdx.x;  // 0..127
  const float* w1r = W1 + g * 256;
  float acc = 0.f;
#pragma unroll 8
  for (int m = 0; m < 256; ++m) acc += w1r[m] * W2[m * NH + o];
  srow[o] = acc;
  __syncthreads();
  float wf = 0.f;
#pragma unroll 8
  for (int j = 0; j < NH; ++j) wf += srow[j] * Wp[(NH + j) * NH + o];
  gWf[g * NH + o] = wf;
}

// 1024-thread version: LDS (155.5 KB) pins us to 1 block/CU regardless, so a
// bigger block doubles occupancy 2->4 waves/SIMD (the r9 stall signature:
// instruction-count model ~100us vs measured 313us = diffuse latency exposure
// at 2 waves/SIMD). All phase thread-maps redistributed; VGPR cap 128 fits.
__global__ __launch_bounds__(1024, 1) void decoder_kernel(
    const float* __restrict__ instance, const int* __restrict__ solution,
    const float* __restrict__ Z, const float* __restrict__ IH,
    const float* __restrict__ last_hh, const float* __restrict__ W_emb,
    const float* __restrict__ b_emb, const float* __restrict__ W_ih,
    const float* __restrict__ W_hh, const float* __restrict__ b_ih,
    const float* __restrict__ b_hh, const float* __restrict__ W_a,
    const float* __restrict__ v_a, const float* __restrict__ W1,
    const float* __restrict__ b1, const float* __restrict__ W2,
    const float* __restrict__ b2, const float* __restrict__ Wp,
    const float* __restrict__ vp, float* __restrict__ gWf,
    float* __restrict__ out) {
  extern __shared__ float sm[];
  int* soli = (int*)(sm + OFF_SOL);
  int* ranki = (int*)(sm + OFF_RANK);
  const int b = blockIdx.x;
  const int t = threadIdx.x;
  const float* ihb = IH + b * NS * NH;

  // ---------- thread-role constants ----------
  const int oc = t >> 3, qc = t & 7;        // chain: 128 outs x 8 k-chunks of 16
  const int oq = (t & 31) * 4, jg = t >> 5; // B/D/P: o-quad x 32 j-strips (i<2)
  const int jj = t >> 4, sq = t & 15;       // C/G/H: 64 rows x 16 lanes (i<4)

  // ================= startup phase 0 =================
  if (t < NS) {
    int sv = solution[b * NS + t];
    soli[t] = sv;
    ranki[sv] = t;
    sm[OFF_REFX + t] = instance[(b * NS + sv) * 2 + 0];
    sm[OFF_REFY + t] = instance[(b * NS + sv) * 2 + 1];
  }
  if (t < NH) {
    sm[OFF_VA + t] = v_a[t];
    sm[OFF_VPV + t] = vp[t];
    sm[OFF_HALL + padh(t)] = last_hh[b * NH + t];  // h0
  }
  if (t < 384) sm[OFF_BHH + t] = b_hh[t];
  // gate-n weights -> LDS slices (512 slices of 32, pitch 33); filled by t<512
  if (t < 512) {
    const int o4 = t >> 2, q4 = t & 3;
    const float* wnp = W_hh + (2 * NH + o4) * NH + 32 * q4;
#pragma unroll
    for (int u4 = 0; u4 < 8; ++u4) {
      float4 w = *(const float4*)(wnp + 4 * u4);
      sm[OFF_WN + t * 33 + 4 * u4 + 0] = w.x;
      sm[OFF_WN + t * 33 + 4 * u4 + 1] = w.y;
      sm[OFF_WN + t * 33 + 4 * u4 + 2] = w.z;
      sm[OFF_WN + t * 33 + 4 * u4 + 3] = w.w;
    }
  }
  // Gpre[c][o3] = [W_emb;b_emb][c] . W_ih[o3,:]  (+ b_ih for c=2)
  if (t < 384) {
    const float* wi = W_ih + t * NH;
    float g0 = 0.f, g1 = 0.f, g2 = 0.f;
#pragma unroll 4
    for (int k4 = 0; k4 < 32; ++k4) {
      float4 w = *(const float4*)(wi + 4 * k4);
      float4 e0 = *(const float4*)(W_emb + 4 * k4);
      float4 e1 = *(const float4*)(W_emb + NH + 4 * k4);
      float4 eb = *(const float4*)(b_emb + 4 * k4);
      g0 += w.x * e0.x + w.y * e0.y + w.z * e0.z + w.w * e0.w;
      g1 += w.x * e1.x + w.y * e1.y + w.z * e1.z + w.w * e1.w;
      g2 += w.x * eb.x + w.y * eb.y + w.z * eb.z + w.w * eb.w;
    }
    sm[OFF_GPRE + t] = g0;
    sm[OFF_GPRE + 384 + t] = g1;
    sm[OFF_GPRE + 768 + t] = g2 + b_ih[t];
  }
  // am[c][m]: fc1 affine inputs (ref_h coords + Z/bias fold)
  if (t < 256) {
    const float* zb = Z + b * NZ;
    float a0 = 0.f, a1 = 0.f, a2 = 0.f;
#pragma unroll 2
    for (int k = 0; k < NH; ++k) {
      float wr = W1[(2 * NH + k) * 256 + t];
      a0 += W_emb[k] * wr;
      a1 += W_emb[NH + k] * wr;
      a2 += b_emb[k] * wr + zb[k] * W1[(NH + k) * 256 + t];
    }
    sm[OFF_AM + t] = a0;
    sm[OFF_AM + 256 + t] = a1;
    sm[OFF_AM + 512 + t] = a2 + b1[t];
  }
  __syncthreads();
  // ================= startup phase 1: v[c] = am[c] @ W2 (+ b2 for c=2) ======
  if (t < 384) {
    const int c = t >> 7, jc = t & 127;
    const float* amc = sm + OFF_AM + c * 256;
    float acc = (c == 2) ? b2[jc] : 0.f;
#pragma unroll 4
    for (int m = 0; m < 256; ++m) acc += amc[m] * W2[m * NH + jc];
    sm[OFF_V2 + t] = acc;
  }
  __syncthreads();
  // ================= startup phase 2: U[c] = v[c] @ Wp[H:] ==================
  if (t < 384) {
    const int c = t >> 7, o = t & 127;
    const float* vc = sm + OFF_V2 + c * NH;
    float acc = 0.f;
#pragma unroll 4
    for (int j = 0; j < NH; ++j) acc += vc[j] * Wp[(NH + j) * NH + o];
    sm[OFF_U + c * NH + o] = acc;
  }
  if (t == 0) out[b * NS] = (float)soli[0];
  __syncthreads();

  // ========== h-chain: the ONLY serial recurrence (63 iters, 1 barrier each).
  // Gates r,z: 32 scalar floats pinned (16 each); gate n: LDS slice (shared
  // pairwise: slice oc*4+(qc>>1), half qc&1).
  {
    float whr[16], whz[16];
    {
      const float* br = W_hh + oc * NH + 16 * qc;
      const float* bz = W_hh + (NH + oc) * NH + 16 * qc;
#pragma unroll
      for (int u4 = 0; u4 < 4; ++u4) {
        float4 r4 = *(const float4*)(br + 4 * u4);
        float4 z4 = *(const float4*)(bz + 4 * u4);
        whr[4 * u4 + 0] = r4.x; whr[4 * u4 + 1] = r4.y;
        whr[4 * u4 + 2] = r4.z; whr[4 * u4 + 3] = r4.w;
        whz[4 * u4 + 0] = z4.x; whz[4 * u4 + 1] = z4.y;
        whz[4 * u4 + 2] = z4.z; whz[4 * u4 + 3] = z4.w;
      }
    }
    PIN8(whr, 0); PIN8(whr, 8);
    PIN8(whz, 0); PIN8(whz, 8);
    const float* wn = sm + OFF_WN + (oc * 4 + (qc >> 1)) * 33 + (qc & 1) * 16;
    const int hoffc = padh(16 * qc);  // 16-float run stays contiguous in padh
    // hoist loop-invariant LDS scalars
    const float bhr = sm[OFF_BHH + oc];
    const float bhz = sm[OFF_BHH + NH + oc];
    const float bhn = sm[OFF_BHH + 2 * NH + oc];
    const float gr0 = sm[OFF_GPRE + oc];
    const float gr1 = sm[OFF_GPRE + 384 + oc];
    const float gr2 = sm[OFF_GPRE + 768 + oc];
    const float gz0 = sm[OFF_GPRE + NH + oc];
    const float gz1 = sm[OFF_GPRE + 384 + NH + oc];
    const float gz2 = sm[OFF_GPRE + 768 + NH + oc];
    const float gn0 = sm[OFF_GPRE + 2 * NH + oc];
    const float gn1 = sm[OFF_GPRE + 384 + 2 * NH + oc];
    const float gn2 = sm[OFF_GPRE + 768 + 2 * NH + oc];
#pragma unroll 1
    for (int j = 1; j <= NSTEPS; ++j) {
      float ar = 0.f, az = 0.f, an = 0.f;
      const float* hp = sm + OFF_HALL + (j - 1) * HP + hoffc;
#pragma unroll
      for (int u = 0; u < 4; ++u) {
        float4 hv = *(const float4*)(hp + 4 * u);
        ar += hv.x * whr[4 * u] + hv.y * whr[4 * u + 1] +
              hv.z * whr[4 * u + 2] + hv.w * whr[4 * u + 3];
        az += hv.x * whz[4 * u] + hv.y * whz[4 * u + 1] +
              hv.z * whz[4 * u + 2] + hv.w * whz[4 * u + 3];
        an += hv.x * wn[4 * u] + hv.y * wn[4 * u + 1] +
              hv.z * wn[4 * u + 2] + hv.w * wn[4 * u + 3];
      }
      ar += __shfl_xor(ar, 1); ar += __shfl_xor(ar, 2); ar += __shfl_xor(ar, 4);
      az += __shfl_xor(az, 1); az += __shfl_xor(az, 2); az += __shfl_xor(az, 4);
      an += __shfl_xor(an, 1); an += __shfl_xor(an, 2); an += __shfl_xor(an, 4);
      if (qc == 0) {
        float r0 = sm[OFF_REFX + (j - 1)], r1 = sm[OFF_REFY + (j - 1)];
        float gir = r0 * gr0 + r1 * gr1 + gr2;
        float giz = r0 * gz0 + r1 * gz1 + gz2;
        float gin = r0 * gn0 + r1 * gn1 + gn2;
        // recurrent path keeps libm precision (compounds over 63 steps)
        float r = 1.f / (1.f + expf(-(gir + ar + bhr)));
        float z = 1.f / (1.f + expf(-(giz + az + bhz)));
        float n = tanhf(gin + r * (an + bhn));
        float hold = sm[OFF_HALL + (j - 1) * HP + padh(oc)];
        sm[OFF_HALL + j * HP + padh(oc)] = (1.f - z) * n + z * hold;
      }
      __syncthreads();
    }
  }

  // ========== stage IH into ATTH region ==========
  for (int i = 4 * t; i < NS * NH; i += 4096)
    *(float4*)(sm + OFF_ATTH + i) = *(const float4*)(ihb + i);
  __syncthreads();
  // ========== preA/preP (overwrites dead WN region) ==========
  {
    const int jx = t & 127, sg = t >> 7;  // sg 0..7, wave-uniform
    float accA[8], accP[8];
#pragma unroll
    for (int si = 0; si < 8; ++si) { accA[si] = 0.f; accP[si] = 0.f; }
#pragma unroll 2
    for (int k4 = 0; k4 < 32; ++k4) {
      const int k = 4 * k4;
      float wa0 = W_a[(k + 0) * NH + jx];
      float wa1 = W_a[(k + 1) * NH + jx];
      float wa2 = W_a[(k + 2) * NH + jx];
      float wa3 = W_a[(k + 3) * NH + jx];
      float wp0 = Wp[(k + 0) * NH + jx];
      float wp1 = Wp[(k + 1) * NH + jx];
      float wp2 = Wp[(k + 2) * NH + jx];
      float wp3 = Wp[(k + 3) * NH + jx];
#pragma unroll
      for (int si = 0; si < 8; ++si) {
        float4 ih = *(const float4*)(sm + OFF_ATTH + (sg * 8 + si) * NH + k);
        accA[si] += ih.x * wa0 + ih.y * wa1 + ih.z * wa2 + ih.w * wa3;
        accP[si] += ih.x * wp0 + ih.y * wp1 + ih.z * wp2 + ih.w * wp3;
      }
    }
#pragma unroll
    for (int si = 0; si < 8; ++si) {
      sm[OFF_PREA + (sg * 8 + si) * PP + jx] = accA[si];
      sm[OFF_PREP + (sg * 8 + si) * PP + jx] = accP[si];
    }
  }
  __syncthreads();

  // ========== B: atthB[j] = h_j @ W_a[H:] (batched; 2 j per thread) ==========
  {
    float4 acc[2];
    acc[0] = (float4){0.f, 0.f, 0.f, 0.f};
    acc[1] = (float4){0.f, 0.f, 0.f, 0.f};
    const float* wbase = W_a + NH * NH + oq;
#pragma unroll 4
    for (int k4 = 0; k4 < 32; ++k4) {
      int k = 4 * k4;
      int hoff = k + 4 * (k4 >> 3);  // padh offset
      float4 w0 = *(const float4*)(wbase + (k + 0) * NH);
      float4 w1 = *(const float4*)(wbase + (k + 1) * NH);
      float4 w2 = *(const float4*)(wbase + (k + 2) * NH);
      float4 w3 = *(const float4*)(wbase + (k + 3) * NH);
#pragma unroll
      for (int i = 0; i < 2; ++i) {
        float4 hv = *(const float4*)(sm + OFF_HALL + (jg + 32 * i) * HP + hoff);
        acc[i].x += hv.x * w0.x + hv.y * w1.x + hv.z * w2.x + hv.w * w3.x;
        acc[i].y += hv.x * w0.y + hv.y * w1.y + hv.z * w2.y + hv.w * w3.y;
        acc[i].z += hv.x * w0.z + hv.y * w1.z + hv.z * w2.z + hv.w * w3.z;
        acc[i].w += hv.x * w0.w + hv.y * w1.w + hv.z * w2.w + hv.w * w3.w;
      }
    }
#pragma unroll
    for (int i = 0; i < 2; ++i)
      *(float4*)(sm + OFF_ATTH + (jg + 32 * i) * PP + oq) = acc[i];
  }
  __syncthreads();

  // ========== C: scores[jj][sq+16i] + FUSED softmax (16-lane group = row) ====
  {
    const float* ah = sm + OFF_ATTH + jj * PP;
    float accv[4] = {0.f, 0.f, 0.f, 0.f};
#pragma unroll 2
    for (int k4 = 0; k4 < 32; ++k4) {
      float4 h = *(const float4*)(ah + 4 * k4);
      float4 v = *(const float4*)(sm + OFF_VA + 4 * k4);
#pragma unroll
      for (int i = 0; i < 4; ++i) {
        float4 a = *(const float4*)(sm + OFF_PREA + (sq + 16 * i) * PP + 4 * k4);
        accv[i] += ftanh(a.x + h.x) * v.x + ftanh(a.y + h.y) * v.y +
                   ftanh(a.z + h.z) * v.z + ftanh(a.w + h.w) * v.w;
      }
    }
    float m = fmaxf(fmaxf(accv[0], accv[1]), fmaxf(accv[2], accv[3]));
    m = fmaxf(m, __shfl_xor(m, 1));
    m = fmaxf(m, __shfl_xor(m, 2));
    m = fmaxf(m, __shfl_xor(m, 4));
    m = fmaxf(m, __shfl_xor(m, 8));
    float p0 = __expf(accv[0] - m), p1 = __expf(accv[1] - m);
    float p2 = __expf(accv[2] - m), p3 = __expf(accv[3] - m);
    float ssum = (p0 + p1) + (p2 + p3);
    ssum += __shfl_xor(ssum, 1); ssum += __shfl_xor(ssum, 2);
    ssum += __shfl_xor(ssum, 4); ssum += __shfl_xor(ssum, 8);
    sm[OFF_SCOR + jj * SP + sq + 0]  = p0 / ssum;
    sm[OFF_SCOR + jj * SP + sq + 16] = p1 / ssum;
    sm[OFF_SCOR + jj * SP + sq + 32] = p2 / ssum;
    sm[OFF_SCOR + jj * SP + sq + 48] = p3 / ssum;
  }
  __syncthreads();

  // ========== D: ctx[j] = attn[j] @ IH (into preA buffer; IH from L2) ==========
  {
    float4 acc[2];
    acc[0] = (float4){0.f, 0.f, 0.f, 0.f};
    acc[1] = (float4){0.f, 0.f, 0.f, 0.f};
    const float* ibase = ihb + oq;
#pragma unroll 4
    for (int s4 = 0; s4 < 16; ++s4) {
      int s = 4 * s4;
      float4 x0 = *(const float4*)(ibase + (s + 0) * NH);
      float4 x1 = *(const float4*)(ibase + (s + 1) * NH);
      float4 x2 = *(const float4*)(ibase + (s + 2) * NH);
      float4 x3 = *(const float4*)(ibase + (s + 3) * NH);
#pragma unroll
      for (int i = 0; i < 2; ++i) {
        const float* at = sm + OFF_SCOR + (jg + 32 * i) * SP + s;
        float a0 = at[0], a1 = at[1], a2 = at[2], a3 = at[3];
        acc[i].x += a0 * x0.x + a1 * x1.x + a2 * x2.x + a3 * x3.x;
        acc[i].y += a0 * x0.y + a1 * x1.y + a2 * x2.y + a3 * x3.y;
        acc[i].z += a0 * x0.z + a1 * x1.z + a2 * x2.z + a3 * x3.z;
        acc[i].w += a0 * x0.w + a1 * x1.w + a2 * x2.w + a3 * x3.w;
      }
    }
#pragma unroll
    for (int i = 0; i < 2; ++i)
      *(float4*)(sm + OFF_PREA + (jg + 32 * i) * PP + oq) = acc[i];
  }
  __syncthreads();

  // ========== P: ptrh[j] = ctx[j] @ Wf + affine (into atth buffer) ==========
  {
    float4 acc[2];
    acc[0] = (float4){0.f, 0.f, 0.f, 0.f};
    acc[1] = (float4){0.f, 0.f, 0.f, 0.f};
    const float* wfb = gWf + oq;
#pragma unroll 4
    for (int k4 = 0; k4 < 32; ++k4) {
      int k = 4 * k4;
      float4 w0 = *(const float4*)(wfb + (k + 0) * NH);
      float4 w1 = *(const float4*)(wfb + (k + 1) * NH);
      float4 w2 = *(const float4*)(wfb + (k + 2) * NH);
      float4 w3 = *(const float4*)(wfb + (k + 3) * NH);
#pragma unroll
      for (int i = 0; i < 2; ++i) {
        float4 cv = *(const float4*)(sm + OFF_PREA + (jg + 32 * i) * PP + k);
        acc[i].x += cv.x * w0.x + cv.y * w1.x + cv.z * w2.x + cv.w * w3.x;
        acc[i].y += cv.x * w0.y + cv.y * w1.y + cv.z * w2.y + cv.w * w3.y;
        acc[i].z += cv.x * w0.z + cv.y * w1.z + cv.z * w2.z + cv.w * w3.z;
        acc[i].w += cv.x * w0.w + cv.y * w1.w + cv.z * w2.w + cv.w * w3.w;
      }
    }
    float4 u0 = *(const float4*)(sm + OFF_U + oq);
    float4 u1 = *(const float4*)(sm + OFF_U + NH + oq);
    float4 u2 = *(const float4*)(sm + OFF_U + 2 * NH + oq);
#pragma unroll
    for (int i = 0; i < 2; ++i) {
      int j = jg + 32 * i;
      int jm = (j > 0) ? (j - 1) : 0;  // row 0 unused; clamp avoids OOB
      float rx = sm[OFF_REFX + jm], ry = sm[OFF_REFY + jm];
      float4 r;
      r.x = acc[i].x + rx * u0.x + ry * u1.x + u2.x;
      r.y = acc[i].y + rx * u0.y + ry * u1.y + u2.y;
      r.z = acc[i].z + rx * u0.z + ry * u1.z + u2.z;
      r.w = acc[i].w + rx * u0.w + ry * u1.w + u2.w;
      *(float4*)(sm + OFF_ATTH + j * PP + oq) = r;
    }
  }
  __syncthreads();

  // ========== G: glogits[jj][sq+16i] -> SCOR ==========
  {
    const float* ph = sm + OFF_ATTH + jj * PP;
    float accv[4] = {0.f, 0.f, 0.f, 0.f};
#pragma unroll 2
    for (int k4 = 0; k4 < 32; ++k4) {
      float4 h = *(const float4*)(ph + 4 * k4);
      float4 v = *(const float4*)(sm + OFF_VPV + 4 * k4);
#pragma unroll
      for (int i = 0; i < 4; ++i) {
        float4 a = *(const float4*)(sm + OFF_PREP + (sq + 16 * i) * PP + 4 * k4);
        accv[i] += ftanh(a.x + h.x) * v.x + ftanh(a.y + h.y) * v.y +
                   ftanh(a.z + h.z) * v.z + ftanh(a.w + h.w) * v.w;
      }
    }
#pragma unroll
    for (int i = 0; i < 4; ++i) sm[OFF_SCOR + jj * SP + sq + 16 * i] = accv[i];
  }
  __syncthreads();

  // ========== H: masked log-softmax + argmax (first-index tie) + outputs =====
  {
    float ml[4];
    float m = -INFINITY;
    int mi = 127;
#pragma unroll
    for (int i = 0; i < 4; ++i) {
      int s = sq + 16 * i;
      float lg = sm[OFF_SCOR + jj * SP + s];
      ml[i] = (ranki[s] >= jj) ? lg : -INFINITY;  // mask excludes sol[0..j-1]
      if (ml[i] > m) { m = ml[i]; mi = s; }       // ascending s: earliest on tie
    }
#pragma unroll
    for (int off = 1; off <= 8; off <<= 1) {
      float om = __shfl_xor(m, off);
      int oi = __shfl_xor(mi, off);
      if (om > m || (om == m && oi < mi)) { m = om; mi = oi; }
    }
    float ssum = 0.f;
#pragma unroll
    for (int i = 0; i < 4; ++i) ssum += __expf(ml[i] - m);
    ssum += __shfl_xor(ssum, 1); ssum += __shfl_xor(ssum, 2);
    ssum += __shfl_xor(ssum, 4); ssum += __shfl_xor(ssum, 8);
    if (sq == 0 && jj >= 1) {
      out[b * NS + jj] = (float)mi;
      float pv = sm[OFF_SCOR + jj * SP + soli[jj]];  // sol[j] unmasked at step j
      out[NB * NS + b * NSTEPS + (jj - 1)] = pv - m - __logf(ssum);
    }
  }
}

extern "C" void kernel_launch(void* const* d_in, const int* in_sizes, int n_in,
                              void* d_out, int out_size, void* d_ws,
                              size_t ws_size, hipStream_t stream) {
  (void)in_sizes; (void)n_in; (void)out_size; (void)ws_size;
  const float* instance = (const float*)d_in[0];
  const int*   solution = (const int*)d_in[1];
  const float* Z        = (const float*)d_in[2];
  const float* IH       = (const float*)d_in[3];
  const float* last_hh  = (const float*)d_in[4];
  const float* W_emb    = (const float*)d_in[5];
  const float* b_emb    = (const float*)d_in[6];
  const float* W_ih     = (const float*)d_in[7];
  const float* W_hh     = (const float*)d_in[8];
  const float* b_ih     = (const float*)d_in[9];
  const float* b_hh     = (const float*)d_in[10];
  const float* W_a      = (const float*)d_in[11];
  const float* v_a      = (const float*)d_in[12];
  const float* W1       = (const float*)d_in[13];
  const float* b1       = (const float*)d_in[14];
  const float* W2       = (const float*)d_in[15];
  const float* b2       = (const float*)d_in[16];
  const float* Wp       = (const float*)d_in[17];
  const float* vp       = (const float*)d_in[18];
  float* out = (float*)d_out;
  float* gWf = (float*)d_ws;  // 64 KB scratch for folded MLP weight

  // pre-kernel: compute Wf once (same stream -> ordered before decoder)
  fold_kernel<<<NH, NH, 0, stream>>>(W1, W2, Wp, gWf);

  const int shmem = SM_FLOATS * 4;
  static_assert(SM_FLOATS * 4 <= 160 * 1024, "LDS overlay too big");
  hipFuncSetAttribute((const void*)decoder_kernel,
                      hipFuncAttributeMaxDynamicSharedMemorySize, shmem);
  decoder_kernel<<<NB, 1024, shmem, stream>>>(
      instance, solution, Z, IH, last_hh, W_emb, b_emb, W_ih, W_hh, b_ih, b_hh,
      W_a, v_a, W1, b1, W2, b2, Wp, vp, gWf, out);
}

// Round 11
// 367.514 us; speedup vs baseline: 1.0206x; 1.0206x over previous
//
#include <hip/hip_runtime.h>
#include <math.h>

#define NB 256
#define NS 64
#define NH 128
#define NZ 128
#define NSTEPS 63
#define HP 144   // HALL row pitch (padh layout within each row)
#define PP 132   // preA/preP/atth(ptrh)/ctx row pitch
#define SP 68    // scores row pitch

// LDS float-offsets (total 39808 floats = 155.5 KiB)
#define OFF_PREA 0       // 8448 (post-chain; WN lives here during startup+chain)
#define OFF_PREP 8448    // 8448 -> [0,16896)
#define OFF_WN   0       // 512*33 = 16896: gate-n weight slices (chain only)
#define OFF_HALL 16896   // 9216 -> [16896,26112)
#define OFF_ATTH 26112   // 8448 -> [26112,34560); post-chain: IH stage, then atth/ptrh
#define OFF_SCOR 34560   // 4352 -> [34560,38912)
#define OFF_U    38912   // 384
#define OFF_VA   39296   // 128
#define OFF_VPV  39424   // 128
#define OFF_REFX 39552   // 64
#define OFF_REFY 39616   // 64
#define OFF_SOL  39680   // 64 (int)
#define OFF_RANK 39744   // 64 (int)
#define SM_FLOATS 39808
// startup temps inside SCOR region (dead before SCOR first written):
#define OFF_GPRE 34560   // 1152
#define OFF_BHH  35712   // 384

// workspace (d_ws) float offsets
#define WS_WF   0        // 16384: (W1[:H]@W2)@Wp[H:]
#define WS_WZ   16384    // 16384: (W1[H:H+ZD]@W2)@Wp[H:]
#define WS_U    32768    // 384:   U0,U1,U2const
#define WS_GPRE 33152    // 1152:  [W_emb;b_emb]@W_ih^T (+b_ih)
#define WS_FLOATS 34304

// +4 pad per 32-float chunk (r1-validated conflict fix for HALL rows)
__device__ __forceinline__ int padh(int i) { return i + ((i >> 5) << 2); }

// fast tanh (validated r1/r4-r10: passes with absmax 0.0)
__device__ __forceinline__ float ftanh(float x) {
  float e = __expf(2.0f * x);
  return 1.0f - 2.0f * __builtin_amdgcn_rcpf(e + 1.0f);
}
// fast sigmoid (same primitive family)
__device__ __forceinline__ float fsigm(float x) {
  return __builtin_amdgcn_rcpf(1.0f + __expf(-x));
}

// pin 8 scalar floats into VGPRs: asm results can't be rematerialized-by-reload
#define PIN8(a, i)                                                          \
  asm volatile("" : "+v"((a)[(i)]), "+v"((a)[(i) + 1]), "+v"((a)[(i) + 2]), \
                    "+v"((a)[(i) + 3]), "+v"((a)[(i) + 4]),                 \
                    "+v"((a)[(i) + 5]), "+v"((a)[(i) + 6]),                 \
                    "+v"((a)[(i) + 7]))

// ---- pre-kernel: ALL b-independent weight algebra, computed ONCE ----
// blocks 0..127:  Wf row g  = (W1[:H]@W2)@Wp[H:]
// blocks 128..255: Wz row k = (W1[H:H+ZD]@W2)@Wp[H:]  (Z-path fold)
// block 0 extra:  U0/U1/U2const vector chains
// blocks 1..3 extra: Gpre (384 rows)
__global__ __launch_bounds__(128, 1) void fold_kernel(
    const float* __restrict__ W1, const float* __restrict__ W2,
    const float* __restrict__ Wp, const float* __restrict__ W_ih,
    const float* __restrict__ W_emb, const float* __restrict__ b_emb,
    const float* __restrict__ b_ih, const float* __restrict__ b1,
    const float* __restrict__ b2, float* __restrict__ ws) {
  __shared__ float srow[NH];
  __shared__ float amS[768];
  __shared__ float vS[384];
  const int g = blockIdx.x;
  const int o = threadIdx.x;  // 0..127
  // two-stage fold for this row
  {
    const int r = (g < 128) ? g : (NH + (g - 128));  // W1 row base (ctx | Z block)
    const float* w1r = W1 + r * 256;
    float acc = 0.f;
#pragma unroll 8
    for (int m = 0; m < 256; ++m) acc += w1r[m] * W2[m * NH + o];
    srow[o] = acc;
    __syncthreads();
    float wf = 0.f;
#pragma unroll 8
    for (int j = 0; j < NH; ++j) wf += srow[j] * Wp[(NH + j) * NH + o];
    if (g < 128) ws[WS_WF + g * NH + o] = wf;
    else         ws[WS_WZ + (g - 128) * NH + o] = wf;
  }
  // Gpre rows (blocks 1..3)
  if (g >= 1 && g <= 3) {
    const int row = (g - 1) * NH + o;
    const float* wi = W_ih + row * NH;
    float g0 = 0.f, g1 = 0.f, g2 = 0.f;
#pragma unroll 4
    for (int k4 = 0; k4 < 32; ++k4) {
      float4 w = *(const float4*)(wi + 4 * k4);
      float4 e0 = *(const float4*)(W_emb + 4 * k4);
      float4 e1 = *(const float4*)(W_emb + NH + 4 * k4);
      float4 eb = *(const float4*)(b_emb + 4 * k4);
      g0 += w.x * e0.x + w.y * e0.y + w.z * e0.z + w.w * e0.w;
      g1 += w.x * e1.x + w.y * e1.y + w.z * e1.z + w.w * e1.w;
      g2 += w.x * eb.x + w.y * eb.y + w.z * eb.z + w.w * eb.w;
    }
    ws[WS_GPRE + row] = g0;
    ws[WS_GPRE + 384 + row] = g1;
    ws[WS_GPRE + 768 + row] = g2 + b_ih[row];
  }
  // U chains (block 0): am[c][256] -> v[c][128] -> U[c][128]
  if (g == 0) {
    __syncthreads();
#pragma unroll
    for (int half = 0; half < 2; ++half) {
      const int m = o + 128 * half;
      float a0 = 0.f, a1 = 0.f, a2 = 0.f;
#pragma unroll 4
      for (int k = 0; k < NH; ++k) {
        float wr = W1[(2 * NH + k) * 256 + m];
        a0 += W_emb[k] * wr;
        a1 += W_emb[NH + k] * wr;
        a2 += b_emb[k] * wr;
      }
      amS[m] = a0;
      amS[256 + m] = a1;
      amS[512 + m] = a2 + b1[m];
    }
    __syncthreads();
#pragma unroll
    for (int c = 0; c < 3; ++c) {
      const float* amc = amS + c * 256;
      float acc = (c == 2) ? b2[o] : 0.f;
#pragma unroll 4
      for (int m = 0; m < 256; ++m) acc += amc[m] * W2[m * NH + o];
      vS[c * NH + o] = acc;
    }
    __syncthreads();
#pragma unroll
    for (int c = 0; c < 3; ++c) {
      const float* vc = vS + c * NH;
      float acc = 0.f;
#pragma unroll 4
      for (int j = 0; j < NH; ++j) acc += vc[j] * Wp[(NH + j) * NH + o];
      ws[WS_U + c * NH + o] = acc;
    }
  }
}

// r10 structure, instruction-dieted: b-independent startup moved to fold;
// GRU gates in fast-math (issue-bound regime: dur flat at 2x occupancy, so
// only instruction-count reduction pays).
__global__ __launch_bounds__(1024, 1) void decoder_kernel(
    const float* __restrict__ instance, const int* __restrict__ solution,
    const float* __restrict__ Z, const float* __restrict__ IH,
    const float* __restrict__ last_hh, const float* __restrict__ W_hh,
    const float* __restrict__ b_hh, const float* __restrict__ W_a,
    const float* __restrict__ v_a, const float* __restrict__ Wp,
    const float* __restrict__ vp, const float* __restrict__ ws,
    float* __restrict__ out) {
  extern __shared__ float sm[];
  int* soli = (int*)(sm + OFF_SOL);
  int* ranki = (int*)(sm + OFF_RANK);
  const int b = blockIdx.x;
  const int t = threadIdx.x;
  const float* ihb = IH + b * NS * NH;

  // ---------- thread-role constants ----------
  const int oc = t >> 3, qc = t & 7;        // chain: 128 outs x 8 k-chunks of 16
  const int oq = (t & 31) * 4, jg = t >> 5; // B/D/P: o-quad x 32 j-strips (i<2)
  const int jj = t >> 4, sq = t & 15;       // C/G/H: 64 rows x 16 lanes (i<4)

  // ================= startup (single phase) =================
  if (t < NS) {
    int sv = solution[b * NS + t];
    soli[t] = sv;
    ranki[sv] = t;
    sm[OFF_REFX + t] = instance[(b * NS + sv) * 2 + 0];
    sm[OFF_REFY + t] = instance[(b * NS + sv) * 2 + 1];
  }
  if (t < NH) {
    sm[OFF_VA + t] = v_a[t];
    sm[OFF_VPV + t] = vp[t];
    sm[OFF_HALL + padh(t)] = last_hh[b * NH + t];  // h0
  }
  if (t < 384) sm[OFF_BHH + t] = b_hh[t];
  // Gpre + U0/U1 from precomputed workspace
  for (int i = t; i < 1152; i += 1024) sm[OFF_GPRE + i] = ws[WS_GPRE + i];
  if (t < 256) sm[OFF_U + t] = ws[WS_U + t];
  // U2 = U2const + Z[b] @ Wz  (the only per-b piece of the MLP affine)
  {
    const float* zb = Z + b * NZ;
    float acc = 0.f;
#pragma unroll 4
    for (int u = 0; u < 16; ++u) {
      int k = 16 * qc + u;
      acc += zb[k] * ws[WS_WZ + k * NH + oc];
    }
    acc += __shfl_xor(acc, 1); acc += __shfl_xor(acc, 2); acc += __shfl_xor(acc, 4);
    if (qc == 0) sm[OFF_U + 2 * NH + oc] = ws[WS_U + 2 * NH + oc] + acc;
  }
  // gate-n weights -> LDS slices (512 slices of 32, pitch 33)
  if (t < 512) {
    const int o4 = t >> 2, q4 = t & 3;
    const float* wnp = W_hh + (2 * NH + o4) * NH + 32 * q4;
#pragma unroll
    for (int u4 = 0; u4 < 8; ++u4) {
      float4 w = *(const float4*)(wnp + 4 * u4);
      sm[OFF_WN + t * 33 + 4 * u4 + 0] = w.x;
      sm[OFF_WN + t * 33 + 4 * u4 + 1] = w.y;
      sm[OFF_WN + t * 33 + 4 * u4 + 2] = w.z;
      sm[OFF_WN + t * 33 + 4 * u4 + 3] = w.w;
    }
  }
  if (t == 0) out[b * NS] = (float)soli[0];
  __syncthreads();

  // ========== h-chain: the ONLY serial recurrence (63 iters, 1 barrier each).
  // Gates r,z: 32 pinned VGPRs; gate n: LDS slice. Fast-math gates (validated
  // primitive family since r1; issue-bound regime makes libm's ~120 instr/iter
  // of divergent whole-wave cost the chain's dominant term).
  {
    float whr[16], whz[16];
    {
      const float* br = W_hh + oc * NH + 16 * qc;
      const float* bz = W_hh + (NH + oc) * NH + 16 * qc;
#pragma unroll
      for (int u4 = 0; u4 < 4; ++u4) {
        float4 r4 = *(const float4*)(br + 4 * u4);
        float4 z4 = *(const float4*)(bz + 4 * u4);
        whr[4 * u4 + 0] = r4.x; whr[4 * u4 + 1] = r4.y;
        whr[4 * u4 + 2] = r4.z; whr[4 * u4 + 3] = r4.w;
        whz[4 * u4 + 0] = z4.x; whz[4 * u4 + 1] = z4.y;
        whz[4 * u4 + 2] = z4.z; whz[4 * u4 + 3] = z4.w;
      }
    }
    PIN8(whr, 0); PIN8(whr, 8);
    PIN8(whz, 0); PIN8(whz, 8);
    const float* wn = sm + OFF_WN + (oc * 4 + (qc >> 1)) * 33 + (qc & 1) * 16;
    const int hoffc = padh(16 * qc);
    // hoist loop-invariant LDS scalars
    const float bhr = sm[OFF_BHH + oc];
    const float bhz = sm[OFF_BHH + NH + oc];
    const float bhn = sm[OFF_BHH + 2 * NH + oc];
    const float gr0 = sm[OFF_GPRE + oc];
    const float gr1 = sm[OFF_GPRE + 384 + oc];
    const float gr2 = sm[OFF_GPRE + 768 + oc];
    const float gz0 = sm[OFF_GPRE + NH + oc];
    const float gz1 = sm[OFF_GPRE + 384 + NH + oc];
    const float gz2 = sm[OFF_GPRE + 768 + NH + oc];
    const float gn0 = sm[OFF_GPRE + 2 * NH + oc];
    const float gn1 = sm[OFF_GPRE + 384 + 2 * NH + oc];
    const float gn2 = sm[OFF_GPRE + 768 + 2 * NH + oc];
#pragma unroll 1
    for (int j = 1; j <= NSTEPS; ++j) {
      float ar = 0.f, az = 0.f, an = 0.f;
      const float* hp = sm + OFF_HALL + (j - 1) * HP + hoffc;
#pragma unroll
      for (int u = 0; u < 4; ++u) {
        float4 hv = *(const float4*)(hp + 4 * u);
        ar += hv.x * whr[4 * u] + hv.y * whr[4 * u + 1] +
              hv.z * whr[4 * u + 2] + hv.w * whr[4 * u + 3];
        az += hv.x * whz[4 * u] + hv.y * whz[4 * u + 1] +
              hv.z * whz[4 * u + 2] + hv.w * whz[4 * u + 3];
        an += hv.x * wn[4 * u] + hv.y * wn[4 * u + 1] +
              hv.z * wn[4 * u + 2] + hv.w * wn[4 * u + 3];
      }
      ar += __shfl_xor(ar, 1); ar += __shfl_xor(ar, 2); ar += __shfl_xor(ar, 4);
      az += __shfl_xor(az, 1); az += __shfl_xor(az, 2); az += __shfl_xor(az, 4);
      an += __shfl_xor(an, 1); an += __shfl_xor(an, 2); an += __shfl_xor(an, 4);
      if (qc == 0) {
        float r0 = sm[OFF_REFX + (j - 1)], r1 = sm[OFF_REFY + (j - 1)];
        float gir = r0 * gr0 + r1 * gr1 + gr2;
        float giz = r0 * gz0 + r1 * gz1 + gz2;
        float gin = r0 * gn0 + r1 * gn1 + gn2;
        float r = fsigm(gir + ar + bhr);
        float z = fsigm(giz + az + bhz);
        float n = ftanh(gin + r * (an + bhn));
        float hold = sm[OFF_HALL + (j - 1) * HP + padh(oc)];
        sm[OFF_HALL + j * HP + padh(oc)] = (1.f - z) * n + z * hold;
      }
      __syncthreads();
    }
  }

  // ========== stage IH into ATTH region ==========
  for (int i = 4 * t; i < NS * NH; i += 4096)
    *(float4*)(sm + OFF_ATTH + i) = *(const float4*)(ihb + i);
  __syncthreads();
  // ========== preA/preP (overwrites dead WN region) ==========
  {
    const int jx = t & 127, sg = t >> 7;  // sg 0..7, wave-uniform
    float accA[8], accP[8];
#pragma unroll
    for (int si = 0; si < 8; ++si) { accA[si] = 0.f; accP[si] = 0.f; }
#pragma unroll 2
    for (int k4 = 0; k4 < 32; ++k4) {
      const int k = 4 * k4;
      float wa0 = W_a[(k + 0) * NH + jx];
      float wa1 = W_a[(k + 1) * NH + jx];
      float wa2 = W_a[(k + 2) * NH + jx];
      float wa3 = W_a[(k + 3) * NH + jx];
      float wp0 = Wp[(k + 0) * NH + jx];
      float wp1 = Wp[(k + 1) * NH + jx];
      float wp2 = Wp[(k + 2) * NH + jx];
      float wp3 = Wp[(k + 3) * NH + jx];
#pragma unroll
      for (int si = 0; si < 8; ++si) {
        float4 ih = *(const float4*)(sm + OFF_ATTH + (sg * 8 + si) * NH + k);
        accA[si] += ih.x * wa0 + ih.y * wa1 + ih.z * wa2 + ih.w * wa3;
        accP[si] += ih.x * wp0 + ih.y * wp1 + ih.z * wp2 + ih.w * wp3;
      }
    }
#pragma unroll
    for (int si = 0; si < 8; ++si) {
      sm[OFF_PREA + (sg * 8 + si) * PP + jx] = accA[si];
      sm[OFF_PREP + (sg * 8 + si) * PP + jx] = accP[si];
    }
  }
  __syncthreads();

  // ========== B: atthB[j] = h_j @ W_a[H:] (batched; 2 j per thread) ==========
  {
    float4 acc[2];
    acc[0] = (float4){0.f, 0.f, 0.f, 0.f};
    acc[1] = (float4){0.f, 0.f, 0.f, 0.f};
    const float* wbase = W_a + NH * NH + oq;
#pragma unroll 4
    for (int k4 = 0; k4 < 32; ++k4) {
      int k = 4 * k4;
      int hoff = k + 4 * (k4 >> 3);  // padh offset
      float4 w0 = *(const float4*)(wbase + (k + 0) * NH);
      float4 w1 = *(const float4*)(wbase + (k + 1) * NH);
      float4 w2 = *(const float4*)(wbase + (k + 2) * NH);
      float4 w3 = *(const float4*)(wbase + (k + 3) * NH);
#pragma unroll
      for (int i = 0; i < 2; ++i) {
        float4 hv = *(const float4*)(sm + OFF_HALL + (jg + 32 * i) * HP + hoff);
        acc[i].x += hv.x * w0.x + hv.y * w1.x + hv.z * w2.x + hv.w * w3.x;
        acc[i].y += hv.x * w0.y + hv.y * w1.y + hv.z * w2.y + hv.w * w3.y;
        acc[i].z += hv.x * w0.z + hv.y * w1.z + hv.z * w2.z + hv.w * w3.z;
        acc[i].w += hv.x * w0.w + hv.y * w1.w + hv.z * w2.w + hv.w * w3.w;
      }
    }
#pragma unroll
    for (int i = 0; i < 2; ++i)
      *(float4*)(sm + OFF_ATTH + (jg + 32 * i) * PP + oq) = acc[i];
  }
  __syncthreads();

  // ========== C: scores[jj][sq+16i] + FUSED softmax (16-lane group = row) ====
  {
    const float* ah = sm + OFF_ATTH + jj * PP;
    float accv[4] = {0.f, 0.f, 0.f, 0.f};
#pragma unroll 2
    for (int k4 = 0; k4 < 32; ++k4) {
      float4 h = *(const float4*)(ah + 4 * k4);
      float4 v = *(const float4*)(sm + OFF_VA + 4 * k4);
#pragma unroll
      for (int i = 0; i < 4; ++i) {
        float4 a = *(const float4*)(sm + OFF_PREA + (sq + 16 * i) * PP + 4 * k4);
        accv[i] += ftanh(a.x + h.x) * v.x + ftanh(a.y + h.y) * v.y +
                   ftanh(a.z + h.z) * v.z + ftanh(a.w + h.w) * v.w;
      }
    }
    float m = fmaxf(fmaxf(accv[0], accv[1]), fmaxf(accv[2], accv[3]));
    m = fmaxf(m, __shfl_xor(m, 1));
    m = fmaxf(m, __shfl_xor(m, 2));
    m = fmaxf(m, __shfl_xor(m, 4));
    m = fmaxf(m, __shfl_xor(m, 8));
    float p0 = __expf(accv[0] - m), p1 = __expf(accv[1] - m);
    float p2 = __expf(accv[2] - m), p3 = __expf(accv[3] - m);
    float ssum = (p0 + p1) + (p2 + p3);
    ssum += __shfl_xor(ssum, 1); ssum += __shfl_xor(ssum, 2);
    ssum += __shfl_xor(ssum, 4); ssum += __shfl_xor(ssum, 8);
    sm[OFF_SCOR + jj * SP + sq + 0]  = p0 / ssum;
    sm[OFF_SCOR + jj * SP + sq + 16] = p1 / ssum;
    sm[OFF_SCOR + jj * SP + sq + 32] = p2 / ssum;
    sm[OFF_SCOR + jj * SP + sq + 48] = p3 / ssum;
  }
  __syncthreads();

  // ========== D: ctx[j] = attn[j] @ IH (into preA buffer; IH from L2) ==========
  {
    float4 acc[2];
    acc[0] = (float4){0.f, 0.f, 0.f, 0.f};
    acc[1] = (float4){0.f, 0.f, 0.f, 0.f};
    const float* ibase = ihb + oq;
#pragma unroll 4
    for (int s4 = 0; s4 < 16; ++s4) {
      int s = 4 * s4;
      float4 x0 = *(const float4*)(ibase + (s + 0) * NH);
      float4 x1 = *(const float4*)(ibase + (s + 1) * NH);
      float4 x2 = *(const float4*)(ibase + (s + 2) * NH);
      float4 x3 = *(const float4*)(ibase + (s + 3) * NH);
#pragma unroll
      for (int i = 0; i < 2; ++i) {
        const float* at = sm + OFF_SCOR + (jg + 32 * i) * SP + s;
        float a0 = at[0], a1 = at[1], a2 = at[2], a3 = at[3];
        acc[i].x += a0 * x0.x + a1 * x1.x + a2 * x2.x + a3 * x3.x;
        acc[i].y += a0 * x0.y + a1 * x1.y + a2 * x2.y + a3 * x3.y;
        acc[i].z += a0 * x0.z + a1 * x1.z + a2 * x2.z + a3 * x3.z;
        acc[i].w += a0 * x0.w + a1 * x1.w + a2 * x2.w + a3 * x3.w;
      }
    }
#pragma unroll
    for (int i = 0; i < 2; ++i)
      *(float4*)(sm + OFF_PREA + (jg + 32 * i) * PP + oq) = acc[i];
  }
  __syncthreads();

  // ========== P: ptrh[j] = ctx[j] @ Wf + affine (into atth buffer) ==========
  {
    float4 acc[2];
    acc[0] = (float4){0.f, 0.f, 0.f, 0.f};
    acc[1] = (float4){0.f, 0.f, 0.f, 0.f};
    const float* wfb = ws + WS_WF + oq;
#pragma unroll 4
    for (int k4 = 0; k4 < 32; ++k4) {
      int k = 4 * k4;
      float4 w0 = *(const float4*)(wfb + (k + 0) * NH);
      float4 w1 = *(const float4*)(wfb + (k + 1) * NH);
      float4 w2 = *(const float4*)(wfb + (k + 2) * NH);
      float4 w3 = *(const float4*)(wfb + (k + 3) * NH);
#pragma unroll
      for (int i = 0; i < 2; ++i) {
        float4 cv = *(const float4*)(sm + OFF_PREA + (jg + 32 * i) * PP + k);
        acc[i].x += cv.x * w0.x + cv.y * w1.x + cv.z * w2.x + cv.w * w3.x;
        acc[i].y += cv.x * w0.y + cv.y * w1.y + cv.z * w2.y + cv.w * w3.y;
        acc[i].z += cv.x * w0.z + cv.y * w1.z + cv.z * w2.z + cv.w * w3.z;
        acc[i].w += cv.x * w0.w + cv.y * w1.w + cv.z * w2.w + cv.w * w3.w;
      }
    }
    float4 u0 = *(const float4*)(sm + OFF_U + oq);
    float4 u1 = *(const float4*)(sm + OFF_U + NH + oq);
    float4 u2 = *(const float4*)(sm + OFF_U + 2 * NH + oq);
#pragma unroll
    for (int i = 0; i < 2; ++i) {
      int j = jg + 32 * i;
      int jm = (j > 0) ? (j - 1) : 0;  // row 0 unused; clamp avoids OOB
      float rx = sm[OFF_REFX + jm], ry = sm[OFF_REFY + jm];
      float4 r;
      r.x = acc[i].x + rx * u0.x + ry * u1.x + u2.x;
      r.y = acc[i].y + rx * u0.y + ry * u1.y + u2.y;
      r.z = acc[i].z + rx * u0.z + ry * u1.z + u2.z;
      r.w = acc[i].w + rx * u0.w + ry * u1.w + u2.w;
      *(float4*)(sm + OFF_ATTH + j * PP + oq) = r;
    }
  }
  __syncthreads();

  // ========== G: glogits[jj][sq+16i] -> SCOR ==========
  {
    const float* ph = sm + OFF_ATTH + jj * PP;
    float accv[4] = {0.f, 0.f, 0.f, 0.f};
#pragma unroll 2
    for (int k4 = 0; k4 < 32; ++k4) {
      float4 h = *(const float4*)(ph + 4 * k4);
      float4 v = *(const float4*)(sm + OFF_VPV + 4 * k4);
#pragma unroll
      for (int i = 0; i < 4; ++i) {
        float4 a = *(const float4*)(sm + OFF_PREP + (sq + 16 * i) * PP + 4 * k4);
        accv[i] += ftanh(a.x + h.x) * v.x + ftanh(a.y + h.y) * v.y +
                   ftanh(a.z + h.z) * v.z + ftanh(a.w + h.w) * v.w;
      }
    }
#pragma unroll
    for (int i = 0; i < 4; ++i) sm[OFF_SCOR + jj * SP + sq + 16 * i] = accv[i];
  }
  __syncthreads();

  // ========== H: masked log-softmax + argmax (first-index tie) + outputs =====
  {
    float ml[4];
    float m = -INFINITY;
    int mi = 127;
#pragma unroll
    for (int i = 0; i < 4; ++i) {
      int s = sq + 16 * i;
      float lg = sm[OFF_SCOR + jj * SP + s];
      ml[i] = (ranki[s] >= jj) ? lg : -INFINITY;  // mask excludes sol[0..j-1]
      if (ml[i] > m) { m = ml[i]; mi = s; }       // ascending s: earliest on tie
    }
#pragma unroll
    for (int off = 1; off <= 8; off <<= 1) {
      float om = __shfl_xor(m, off);
      int oi = __shfl_xor(mi, off);
      if (om > m || (om == m && oi < mi)) { m = om; mi = oi; }
    }
    float ssum = 0.f;
#pragma unroll
    for (int i = 0; i < 4; ++i) ssum += __expf(ml[i] - m);
    ssum += __shfl_xor(ssum, 1); ssum += __shfl_xor(ssum, 2);
    ssum += __shfl_xor(ssum, 4); ssum += __shfl_xor(ssum, 8);
    if (sq == 0 && jj >= 1) {
      out[b * NS + jj] = (float)mi;
      float pv = sm[OFF_SCOR + jj * SP + soli[jj]];  // sol[j] unmasked at step j
      out[NB * NS + b * NSTEPS + (jj - 1)] = pv - m - __logf(ssum);
    }
  }
}

extern "C" void kernel_launch(void* const* d_in, const int* in_sizes, int n_in,
                              void* d_out, int out_size, void* d_ws,
                              size_t ws_size, hipStream_t stream) {
  (void)in_sizes; (void)n_in; (void)out_size; (void)ws_size;
  const float* instance = (const float*)d_in[0];
  const int*   solution = (const int*)d_in[1];
  const float* Z        = (const float*)d_in[2];
  const float* IH       = (const float*)d_in[3];
  const float* last_hh  = (const float*)d_in[4];
  const float* W_emb    = (const float*)d_in[5];
  const float* b_emb    = (const float*)d_in[6];
  const float* W_ih     = (const float*)d_in[7];
  const float* W_hh     = (const float*)d_in[8];
  const float* b_ih     = (const float*)d_in[9];
  const float* b_hh     = (const float*)d_in[10];
  const float* W_a      = (const float*)d_in[11];
  const float* v_a      = (const float*)d_in[12];
  const float* W1       = (const float*)d_in[13];
  const float* b1       = (const float*)d_in[14];
  const float* W2       = (const float*)d_in[15];
  const float* b2       = (const float*)d_in[16];
  const float* Wp       = (const float*)d_in[17];
  const float* vp       = (const float*)d_in[18];
  float* out = (float*)d_out;
  float* ws = (float*)d_ws;  // 137 KB scratch: Wf, Wz, U, Gpre

  // pre-kernel: all b-independent weight algebra, once (same stream -> ordered)
  fold_kernel<<<256, 128, 0, stream>>>(W1, W2, Wp, W_ih, W_emb, b_emb, b_ih,
                                       b1, b2, ws);

  const int shmem = SM_FLOATS * 4;
  static_assert(SM_FLOATS * 4 <= 160 * 1024, "LDS overlay too big");
  hipFuncSetAttribute((const void*)decoder_kernel,
                      hipFuncAttributeMaxDynamicSharedMemorySize, shmem);
  decoder_kernel<<<NB, 1024, shmem, stream>>>(
      instance, solution, Z, IH, last_hh, W_hh, b_hh, W_a, v_a, Wp, vp, ws,
      out);
}

// Round 12
// 299.434 us; speedup vs baseline: 1.2527x; 1.2274x over previous
//
#include <hip/hip_runtime.h>
#include <math.h>

#define NB 256
#define NS 64
#define NH 128
#define NZ 128
#define NSTEPS 63
#define HP 144   // HALL row pitch (padh layout within each row)
#define PP 132   // preA/preP/atth(ptrh)/ctx row pitch
#define SP 68    // scores row pitch

// LDS float-offsets (total 39808 floats = 155.5 KiB)
#define OFF_PREA 0       // 8448 (post-chain; WN lives here during startup+chain)
#define OFF_PREP 8448    // 8448 -> [0,16896)
#define OFF_WN   0       // 512*33 = 16896: gate-n weight slices (chain only)
#define OFF_HALL 16896   // 9216 -> [16896,26112)
#define OFF_ATTH 26112   // 8448 -> [26112,34560); post-chain: IH stage, then atth/ptrh
#define OFF_SCOR 34560   // 4352 -> [34560,38912)
#define OFF_U    38912   // 384
#define OFF_VA   39296   // 128
#define OFF_VPV  39424   // 128
#define OFF_REFX 39552   // 64
#define OFF_REFY 39616   // 64
#define OFF_SOL  39680   // 64 (int)
#define OFF_RANK 39744   // 64 (int)
#define SM_FLOATS 39808
// startup temps inside SCOR region (dead before SCOR first written):
#define OFF_GPRE 34560   // 1152
#define OFF_BHH  35712   // 384

// workspace (d_ws) float offsets
#define WS_WF   0        // 16384: (W1[:H]@W2)@Wp[H:]
#define WS_WZ   16384    // 16384: (W1[H:H+ZD]@W2)@Wp[H:]
#define WS_U    32768    // 384:   U0,U1,U2const
#define WS_GPRE 33152    // 1152:  [W_emb;b_emb]@W_ih^T (+b_ih)
#define WS_FLOATS 34304

// +4 pad per 32-float chunk (r1-validated conflict fix for HALL rows)
__device__ __forceinline__ int padh(int i) { return i + ((i >> 5) << 2); }

// fast tanh (validated r1/r4-r11: passes)
__device__ __forceinline__ float ftanh(float x) {
  float e = __expf(2.0f * x);
  return 1.0f - 2.0f * __builtin_amdgcn_rcpf(e + 1.0f);
}
// fast sigmoid (validated r11)
__device__ __forceinline__ float fsigm(float x) {
  return __builtin_amdgcn_rcpf(1.0f + __expf(-x));
}
// tanh-addition: tanh(x+y) from tx=tanh(x), ty=tanh(y). Exact identity;
// denominator in (0,2) since |tx|,|ty|<1. 1 trans vs 2 in direct form.
__device__ __forceinline__ float tadd(float tx, float ty) {
  return (tx + ty) * __builtin_amdgcn_rcpf(fmaf(tx, ty, 1.0f));
}

// pin 8 scalar floats into VGPRs: asm results can't be rematerialized-by-reload
#define PIN8(a, i)                                                          \
  asm volatile("" : "+v"((a)[(i)]), "+v"((a)[(i) + 1]), "+v"((a)[(i) + 2]), \
                    "+v"((a)[(i) + 3]), "+v"((a)[(i) + 4]),                 \
                    "+v"((a)[(i) + 5]), "+v"((a)[(i) + 6]),                 \
                    "+v"((a)[(i) + 7]))

// ---- pre-kernel: ALL b-independent weight algebra, computed ONCE ----
// blocks 0..127:  Wf row g  = (W1[:H]@W2)@Wp[H:]
// blocks 128..255: Wz row k = (W1[H:H+ZD]@W2)@Wp[H:]
// blocks 1..3 extra: Gpre (384 rows)
// blocks 256..258: U-chain, one affine channel c each (parallel, not serial
// in block 0 — r11's block-0 3-stage serial chain was ~40us of launch tail)
__global__ __launch_bounds__(128, 1) void fold_kernel(
    const float* __restrict__ W1, const float* __restrict__ W2,
    const float* __restrict__ Wp, const float* __restrict__ W_ih,
    const float* __restrict__ W_emb, const float* __restrict__ b_emb,
    const float* __restrict__ b_ih, const float* __restrict__ b1,
    const float* __restrict__ b2, float* __restrict__ ws) {
  __shared__ float srow[NH];
  __shared__ float amS[256];
  const int g = blockIdx.x;
  const int o = threadIdx.x;  // 0..127
  if (g < 256) {
    // two-stage fold for this row
    const int r = (g < 128) ? g : (NH + (g - 128));
    const float* w1r = W1 + r * 256;
    float acc = 0.f;
#pragma unroll 16
    for (int m = 0; m < 256; ++m) acc += w1r[m] * W2[m * NH + o];
    srow[o] = acc;
    __syncthreads();
    float wf = 0.f;
#pragma unroll 16
    for (int j = 0; j < NH; ++j) wf += srow[j] * Wp[(NH + j) * NH + o];
    if (g < 128) ws[WS_WF + g * NH + o] = wf;
    else         ws[WS_WZ + (g - 128) * NH + o] = wf;
    // Gpre rows (blocks 1..3)
    if (g >= 1 && g <= 3) {
      const int row = (g - 1) * NH + o;
      const float* wi = W_ih + row * NH;
      float g0 = 0.f, g1 = 0.f, g2 = 0.f;
#pragma unroll 8
      for (int k4 = 0; k4 < 32; ++k4) {
        float4 w = *(const float4*)(wi + 4 * k4);
        float4 e0 = *(const float4*)(W_emb + 4 * k4);
        float4 e1 = *(const float4*)(W_emb + NH + 4 * k4);
        float4 eb = *(const float4*)(b_emb + 4 * k4);
        g0 += w.x * e0.x + w.y * e0.y + w.z * e0.z + w.w * e0.w;
        g1 += w.x * e1.x + w.y * e1.y + w.z * e1.z + w.w * e1.w;
        g2 += w.x * eb.x + w.y * eb.y + w.z * eb.z + w.w * eb.w;
      }
      ws[WS_GPRE + row] = g0;
      ws[WS_GPRE + 384 + row] = g1;
      ws[WS_GPRE + 768 + row] = g2 + b_ih[row];
    }
  } else {
    // U-chain for channel c: am[256] -> v[128] -> U[128]
    const int c = g - 256;  // 0:emb_x 1:emb_y 2:bias
    const float* ev = (c == 0) ? W_emb : (c == 1) ? (W_emb + NH) : b_emb;
#pragma unroll
    for (int half = 0; half < 2; ++half) {
      const int m = o + 128 * half;
      float a = 0.f;
#pragma unroll 8
      for (int k = 0; k < NH; ++k) a += ev[k] * W1[(2 * NH + k) * 256 + m];
      amS[m] = (c == 2) ? (a + b1[m]) : a;
    }
    __syncthreads();
    float vv = (c == 2) ? b2[o] : 0.f;
#pragma unroll 16
    for (int m = 0; m < 256; ++m) vv += amS[m] * W2[m * NH + o];
    srow[o] = vv;
    __syncthreads();
    float U = 0.f;
#pragma unroll 16
    for (int j = 0; j < NH; ++j) U += srow[j] * Wp[(NH + j) * NH + o];
    ws[WS_U + c * NH + o] = U;
  }
}

// r11 structure + tanh-addition-formula in C/G: tanh applied once at the four
// producers (preA/preP/atth/ptrh); the 1M-element score loops use
// (Ta+Th)/(1+Ta*Th) — 1 trans op instead of 2, ~35% fewer cycles in the two
// dominant phases (issue-bound regime).
__global__ __launch_bounds__(1024, 1) void decoder_kernel(
    const float* __restrict__ instance, const int* __restrict__ solution,
    const float* __restrict__ Z, const float* __restrict__ IH,
    const float* __restrict__ last_hh, const float* __restrict__ W_hh,
    const float* __restrict__ b_hh, const float* __restrict__ W_a,
    const float* __restrict__ v_a, const float* __restrict__ Wp,
    const float* __restrict__ vp, const float* __restrict__ ws,
    float* __restrict__ out) {
  extern __shared__ float sm[];
  int* soli = (int*)(sm + OFF_SOL);
  int* ranki = (int*)(sm + OFF_RANK);
  const int b = blockIdx.x;
  const int t = threadIdx.x;
  const float* ihb = IH + b * NS * NH;

  // ---------- thread-role constants ----------
  const int oc = t >> 3, qc = t & 7;        // chain: 128 outs x 8 k-chunks of 16
  const int oq = (t & 31) * 4, jg = t >> 5; // B/D/P: o-quad x 32 j-strips (i<2)
  const int jj = t >> 4, sq = t & 15;       // C/G/H: 64 rows x 16 lanes (i<4)

  // ================= startup (single phase) =================
  if (t < NS) {
    int sv = solution[b * NS + t];
    soli[t] = sv;
    ranki[sv] = t;
    sm[OFF_REFX + t] = instance[(b * NS + sv) * 2 + 0];
    sm[OFF_REFY + t] = instance[(b * NS + sv) * 2 + 1];
  }
  if (t < NH) {
    sm[OFF_VA + t] = v_a[t];
    sm[OFF_VPV + t] = vp[t];
    sm[OFF_HALL + padh(t)] = last_hh[b * NH + t];  // h0
  }
  if (t < 384) sm[OFF_BHH + t] = b_hh[t];
  // Gpre + U0/U1 from precomputed workspace
  for (int i = t; i < 1152; i += 1024) sm[OFF_GPRE + i] = ws[WS_GPRE + i];
  if (t < 256) sm[OFF_U + t] = ws[WS_U + t];
  // U2 = U2const + Z[b] @ Wz  (the only per-b piece of the MLP affine)
  {
    const float* zb = Z + b * NZ;
    float acc = 0.f;
#pragma unroll 4
    for (int u = 0; u < 16; ++u) {
      int k = 16 * qc + u;
      acc += zb[k] * ws[WS_WZ + k * NH + oc];
    }
    acc += __shfl_xor(acc, 1); acc += __shfl_xor(acc, 2); acc += __shfl_xor(acc, 4);
    if (qc == 0) sm[OFF_U + 2 * NH + oc] = ws[WS_U + 2 * NH + oc] + acc;
  }
  // gate-n weights -> LDS slices (512 slices of 32, pitch 33)
  if (t < 512) {
    const int o4 = t >> 2, q4 = t & 3;
    const float* wnp = W_hh + (2 * NH + o4) * NH + 32 * q4;
#pragma unroll
    for (int u4 = 0; u4 < 8; ++u4) {
      float4 w = *(const float4*)(wnp + 4 * u4);
      sm[OFF_WN + t * 33 + 4 * u4 + 0] = w.x;
      sm[OFF_WN + t * 33 + 4 * u4 + 1] = w.y;
      sm[OFF_WN + t * 33 + 4 * u4 + 2] = w.z;
      sm[OFF_WN + t * 33 + 4 * u4 + 3] = w.w;
    }
  }
  if (t == 0) out[b * NS] = (float)soli[0];
  __syncthreads();

  // ========== h-chain: the ONLY serial recurrence (63 iters, 1 barrier each).
  {
    float whr[16], whz[16];
    {
      const float* br = W_hh + oc * NH + 16 * qc;
      const float* bz = W_hh + (NH + oc) * NH + 16 * qc;
#pragma unroll
      for (int u4 = 0; u4 < 4; ++u4) {
        float4 r4 = *(const float4*)(br + 4 * u4);
        float4 z4 = *(const float4*)(bz + 4 * u4);
        whr[4 * u4 + 0] = r4.x; whr[4 * u4 + 1] = r4.y;
        whr[4 * u4 + 2] = r4.z; whr[4 * u4 + 3] = r4.w;
        whz[4 * u4 + 0] = z4.x; whz[4 * u4 + 1] = z4.y;
        whz[4 * u4 + 2] = z4.z; whz[4 * u4 + 3] = z4.w;
      }
    }
    PIN8(whr, 0); PIN8(whr, 8);
    PIN8(whz, 0); PIN8(whz, 8);
    const float* wn = sm + OFF_WN + (oc * 4 + (qc >> 1)) * 33 + (qc & 1) * 16;
    const int hoffc = padh(16 * qc);
    // hoist loop-invariant LDS scalars
    const float bhr = sm[OFF_BHH + oc];
    const float bhz = sm[OFF_BHH + NH + oc];
    const float bhn = sm[OFF_BHH + 2 * NH + oc];
    const float gr0 = sm[OFF_GPRE + oc];
    const float gr1 = sm[OFF_GPRE + 384 + oc];
    const float gr2 = sm[OFF_GPRE + 768 + oc];
    const float gz0 = sm[OFF_GPRE + NH + oc];
    const float gz1 = sm[OFF_GPRE + 384 + NH + oc];
    const float gz2 = sm[OFF_GPRE + 768 + NH + oc];
    const float gn0 = sm[OFF_GPRE + 2 * NH + oc];
    const float gn1 = sm[OFF_GPRE + 384 + 2 * NH + oc];
    const float gn2 = sm[OFF_GPRE + 768 + 2 * NH + oc];
#pragma unroll 1
    for (int j = 1; j <= NSTEPS; ++j) {
      float ar = 0.f, az = 0.f, an = 0.f;
      const float* hp = sm + OFF_HALL + (j - 1) * HP + hoffc;
#pragma unroll
      for (int u = 0; u < 4; ++u) {
        float4 hv = *(const float4*)(hp + 4 * u);
        ar += hv.x * whr[4 * u] + hv.y * whr[4 * u + 1] +
              hv.z * whr[4 * u + 2] + hv.w * whr[4 * u + 3];
        az += hv.x * whz[4 * u] + hv.y * whz[4 * u + 1] +
              hv.z * whz[4 * u + 2] + hv.w * whz[4 * u + 3];
        an += hv.x * wn[4 * u] + hv.y * wn[4 * u + 1] +
              hv.z * wn[4 * u + 2] + hv.w * wn[4 * u + 3];
      }
      ar += __shfl_xor(ar, 1); ar += __shfl_xor(ar, 2); ar += __shfl_xor(ar, 4);
      az += __shfl_xor(az, 1); az += __shfl_xor(az, 2); az += __shfl_xor(az, 4);
      an += __shfl_xor(an, 1); an += __shfl_xor(an, 2); an += __shfl_xor(an, 4);
      if (qc == 0) {
        float r0 = sm[OFF_REFX + (j - 1)], r1 = sm[OFF_REFY + (j - 1)];
        float gir = r0 * gr0 + r1 * gr1 + gr2;
        float giz = r0 * gz0 + r1 * gz1 + gz2;
        float gin = r0 * gn0 + r1 * gn1 + gn2;
        float r = fsigm(gir + ar + bhr);
        float z = fsigm(giz + az + bhz);
        float n = ftanh(gin + r * (an + bhn));
        float hold = sm[OFF_HALL + (j - 1) * HP + padh(oc)];
        sm[OFF_HALL + j * HP + padh(oc)] = (1.f - z) * n + z * hold;
      }
      __syncthreads();
    }
  }

  // ========== stage IH into ATTH region ==========
  for (int i = 4 * t; i < NS * NH; i += 4096)
    *(float4*)(sm + OFF_ATTH + i) = *(const float4*)(ihb + i);
  __syncthreads();
  // ========== preA/preP -> stored as tanh(.) (overwrites dead WN region) =====
  {
    const int jx = t & 127, sg = t >> 7;  // sg 0..7, wave-uniform
    float accA[8], accP[8];
#pragma unroll
    for (int si = 0; si < 8; ++si) { accA[si] = 0.f; accP[si] = 0.f; }
#pragma unroll 2
    for (int k4 = 0; k4 < 32; ++k4) {
      const int k = 4 * k4;
      float wa0 = W_a[(k + 0) * NH + jx];
      float wa1 = W_a[(k + 1) * NH + jx];
      float wa2 = W_a[(k + 2) * NH + jx];
      float wa3 = W_a[(k + 3) * NH + jx];
      float wp0 = Wp[(k + 0) * NH + jx];
      float wp1 = Wp[(k + 1) * NH + jx];
      float wp2 = Wp[(k + 2) * NH + jx];
      float wp3 = Wp[(k + 3) * NH + jx];
#pragma unroll
      for (int si = 0; si < 8; ++si) {
        float4 ih = *(const float4*)(sm + OFF_ATTH + (sg * 8 + si) * NH + k);
        accA[si] += ih.x * wa0 + ih.y * wa1 + ih.z * wa2 + ih.w * wa3;
        accP[si] += ih.x * wp0 + ih.y * wp1 + ih.z * wp2 + ih.w * wp3;
      }
    }
#pragma unroll
    for (int si = 0; si < 8; ++si) {
      sm[OFF_PREA + (sg * 8 + si) * PP + jx] = ftanh(accA[si]);
      sm[OFF_PREP + (sg * 8 + si) * PP + jx] = ftanh(accP[si]);
    }
  }
  __syncthreads();

  // ========== B: atthB[j] = h_j @ W_a[H:] -> stored as tanh(.) ==========
  {
    float4 acc[2];
    acc[0] = (float4){0.f, 0.f, 0.f, 0.f};
    acc[1] = (float4){0.f, 0.f, 0.f, 0.f};
    const float* wbase = W_a + NH * NH + oq;
#pragma unroll 4
    for (int k4 = 0; k4 < 32; ++k4) {
      int k = 4 * k4;
      int hoff = k + 4 * (k4 >> 3);  // padh offset
      float4 w0 = *(const float4*)(wbase + (k + 0) * NH);
      float4 w1 = *(const float4*)(wbase + (k + 1) * NH);
      float4 w2 = *(const float4*)(wbase + (k + 2) * NH);
      float4 w3 = *(const float4*)(wbase + (k + 3) * NH);
#pragma unroll
      for (int i = 0; i < 2; ++i) {
        float4 hv = *(const float4*)(sm + OFF_HALL + (jg + 32 * i) * HP + hoff);
        acc[i].x += hv.x * w0.x + hv.y * w1.x + hv.z * w2.x + hv.w * w3.x;
        acc[i].y += hv.x * w0.y + hv.y * w1.y + hv.z * w2.y + hv.w * w3.y;
        acc[i].z += hv.x * w0.z + hv.y * w1.z + hv.z * w2.z + hv.w * w3.z;
        acc[i].w += hv.x * w0.w + hv.y * w1.w + hv.z * w2.w + hv.w * w3.w;
      }
    }
#pragma unroll
    for (int i = 0; i < 2; ++i) {
      float4 tv;
      tv.x = ftanh(acc[i].x); tv.y = ftanh(acc[i].y);
      tv.z = ftanh(acc[i].z); tv.w = ftanh(acc[i].w);
      *(float4*)(sm + OFF_ATTH + (jg + 32 * i) * PP + oq) = tv;
    }
  }
  __syncthreads();

  // ========== C: scores via tanh-addition + FUSED softmax ==========
  {
    const float* ah = sm + OFF_ATTH + jj * PP;
    float accv[4] = {0.f, 0.f, 0.f, 0.f};
#pragma unroll 2
    for (int k4 = 0; k4 < 32; ++k4) {
      float4 h = *(const float4*)(ah + 4 * k4);
      float4 v = *(const float4*)(sm + OFF_VA + 4 * k4);
#pragma unroll
      for (int i = 0; i < 4; ++i) {
        float4 a = *(const float4*)(sm + OFF_PREA + (sq + 16 * i) * PP + 4 * k4);
        accv[i] += tadd(a.x, h.x) * v.x + tadd(a.y, h.y) * v.y +
                   tadd(a.z, h.z) * v.z + tadd(a.w, h.w) * v.w;
      }
    }
    float m = fmaxf(fmaxf(accv[0], accv[1]), fmaxf(accv[2], accv[3]));
    m = fmaxf(m, __shfl_xor(m, 1));
    m = fmaxf(m, __shfl_xor(m, 2));
    m = fmaxf(m, __shfl_xor(m, 4));
    m = fmaxf(m, __shfl_xor(m, 8));
    float p0 = __expf(accv[0] - m), p1 = __expf(accv[1] - m);
    float p2 = __expf(accv[2] - m), p3 = __expf(accv[3] - m);
    float ssum = (p0 + p1) + (p2 + p3);
    ssum += __shfl_xor(ssum, 1); ssum += __shfl_xor(ssum, 2);
    ssum += __shfl_xor(ssum, 4); ssum += __shfl_xor(ssum, 8);
    sm[OFF_SCOR + jj * SP + sq + 0]  = p0 / ssum;
    sm[OFF_SCOR + jj * SP + sq + 16] = p1 / ssum;
    sm[OFF_SCOR + jj * SP + sq + 32] = p2 / ssum;
    sm[OFF_SCOR + jj * SP + sq + 48] = p3 / ssum;
  }
  __syncthreads();

  // ========== D: ctx[j] = attn[j] @ IH (into preA buffer; IH from L2) ==========
  {
    float4 acc[2];
    acc[0] = (float4){0.f, 0.f, 0.f, 0.f};
    acc[1] = (float4){0.f, 0.f, 0.f, 0.f};
    const float* ibase = ihb + oq;
#pragma unroll 4
    for (int s4 = 0; s4 < 16; ++s4) {
      int s = 4 * s4;
      float4 x0 = *(const float4*)(ibase + (s + 0) * NH);
      float4 x1 = *(const float4*)(ibase + (s + 1) * NH);
      float4 x2 = *(const float4*)(ibase + (s + 2) * NH);
      float4 x3 = *(const float4*)(ibase + (s + 3) * NH);
#pragma unroll
      for (int i = 0; i < 2; ++i) {
        const float* at = sm + OFF_SCOR + (jg + 32 * i) * SP + s;
        float a0 = at[0], a1 = at[1], a2 = at[2], a3 = at[3];
        acc[i].x += a0 * x0.x + a1 * x1.x + a2 * x2.x + a3 * x3.x;
        acc[i].y += a0 * x0.y + a1 * x1.y + a2 * x2.y + a3 * x3.y;
        acc[i].z += a0 * x0.z + a1 * x1.z + a2 * x2.z + a3 * x3.z;
        acc[i].w += a0 * x0.w + a1 * x1.w + a2 * x2.w + a3 * x3.w;
      }
    }
#pragma unroll
    for (int i = 0; i < 2; ++i)
      *(float4*)(sm + OFF_PREA + (jg + 32 * i) * PP + oq) = acc[i];
  }
  __syncthreads();

  // ========== P: ptrh[j] = ctx[j] @ Wf + affine -> stored as tanh(.) =========
  {
    float4 acc[2];
    acc[0] = (float4){0.f, 0.f, 0.f, 0.f};
    acc[1] = (float4){0.f, 0.f, 0.f, 0.f};
    const float* wfb = ws + WS_WF + oq;
#pragma unroll 4
    for (int k4 = 0; k4 < 32; ++k4) {
      int k = 4 * k4;
      float4 w0 = *(const float4*)(wfb + (k + 0) * NH);
      float4 w1 = *(const float4*)(wfb + (k + 1) * NH);
      float4 w2 = *(const float4*)(wfb + (k + 2) * NH);
      float4 w3 = *(const float4*)(wfb + (k + 3) * NH);
#pragma unroll
      for (int i = 0; i < 2; ++i) {
        float4 cv = *(const float4*)(sm + OFF_PREA + (jg + 32 * i) * PP + k);
        acc[i].x += cv.x * w0.x + cv.y * w1.x + cv.z * w2.x + cv.w * w3.x;
        acc[i].y += cv.x * w0.y + cv.y * w1.y + cv.z * w2.y + cv.w * w3.y;
        acc[i].z += cv.x * w0.z + cv.y * w1.z + cv.z * w2.z + cv.w * w3.z;
        acc[i].w += cv.x * w0.w + cv.y * w1.w + cv.z * w2.w + cv.w * w3.w;
      }
    }
    float4 u0 = *(const float4*)(sm + OFF_U + oq);
    float4 u1 = *(const float4*)(sm + OFF_U + NH + oq);
    float4 u2 = *(const float4*)(sm + OFF_U + 2 * NH + oq);
#pragma unroll
    for (int i = 0; i < 2; ++i) {
      int j = jg + 32 * i;
      int jm = (j > 0) ? (j - 1) : 0;  // row 0 unused; clamp avoids OOB
      float rx = sm[OFF_REFX + jm], ry = sm[OFF_REFY + jm];
      float4 r;
      r.x = ftanh(acc[i].x + rx * u0.x + ry * u1.x + u2.x);
      r.y = ftanh(acc[i].y + rx * u0.y + ry * u1.y + u2.y);
      r.z = ftanh(acc[i].z + rx * u0.z + ry * u1.z + u2.z);
      r.w = ftanh(acc[i].w + rx * u0.w + ry * u1.w + u2.w);
      *(float4*)(sm + OFF_ATTH + j * PP + oq) = r;
    }
  }
  __syncthreads();

  // ========== G: glogits via tanh-addition -> SCOR ==========
  {
    const float* ph = sm + OFF_ATTH + jj * PP;
    float accv[4] = {0.f, 0.f, 0.f, 0.f};
#pragma unroll 2
    for (int k4 = 0; k4 < 32; ++k4) {
      float4 h = *(const float4*)(ph + 4 * k4);
      float4 v = *(const float4*)(sm + OFF_VPV + 4 * k4);
#pragma unroll
      for (int i = 0; i < 4; ++i) {
        float4 a = *(const float4*)(sm + OFF_PREP + (sq + 16 * i) * PP + 4 * k4);
        accv[i] += tadd(a.x, h.x) * v.x + tadd(a.y, h.y) * v.y +
                   tadd(a.z, h.z) * v.z + tadd(a.w, h.w) * v.w;
      }
    }
#pragma unroll
    for (int i = 0; i < 4; ++i) sm[OFF_SCOR + jj * SP + sq + 16 * i] = accv[i];
  }
  __syncthreads();

  // ========== H: masked log-softmax + argmax (first-index tie) + outputs =====
  {
    float ml[4];
    float m = -INFINITY;
    int mi = 127;
#pragma unroll
    for (int i = 0; i < 4; ++i) {
      int s = sq + 16 * i;
      float lg = sm[OFF_SCOR + jj * SP + s];
      ml[i] = (ranki[s] >= jj) ? lg : -INFINITY;  // mask excludes sol[0..j-1]
      if (ml[i] > m) { m = ml[i]; mi = s; }       // ascending s: earliest on tie
    }
#pragma unroll
    for (int off = 1; off <= 8; off <<= 1) {
      float om = __shfl_xor(m, off);
      int oi = __shfl_xor(mi, off);
      if (om > m || (om == m && oi < mi)) { m = om; mi = oi; }
    }
    float ssum = 0.f;
#pragma unroll
    for (int i = 0; i < 4; ++i) ssum += __expf(ml[i] - m);
    ssum += __shfl_xor(ssum, 1); ssum += __shfl_xor(ssum, 2);
    ssum += __shfl_xor(ssum, 4); ssum += __shfl_xor(ssum, 8);
    if (sq == 0 && jj >= 1) {
      out[b * NS + jj] = (float)mi;
      float pv = sm[OFF_SCOR + jj * SP + soli[jj]];  // sol[j] unmasked at step j
      out[NB * NS + b * NSTEPS + (jj - 1)] = pv - m - __logf(ssum);
    }
  }
}

extern "C" void kernel_launch(void* const* d_in, const int* in_sizes, int n_in,
                              void* d_out, int out_size, void* d_ws,
                              size_t ws_size, hipStream_t stream) {
  (void)in_sizes; (void)n_in; (void)out_size; (void)ws_size;
  const float* instance = (const float*)d_in[0];
  const int*   solution = (const int*)d_in[1];
  const float* Z        = (const float*)d_in[2];
  const float* IH       = (const float*)d_in[3];
  const float* last_hh  = (const float*)d_in[4];
  const float* W_emb    = (const float*)d_in[5];
  const float* b_emb    = (const float*)d_in[6];
  const float* W_ih     = (const float*)d_in[7];
  const float* W_hh     = (const float*)d_in[8];
  const float* b_ih     = (const float*)d_in[9];
  const float* b_hh     = (const float*)d_in[10];
  const float* W_a      = (const float*)d_in[11];
  const float* v_a      = (const float*)d_in[12];
  const float* W1       = (const float*)d_in[13];
  const float* b1       = (const float*)d_in[14];
  const float* W2       = (const float*)d_in[15];
  const float* b2       = (const float*)d_in[16];
  const float* Wp       = (const float*)d_in[17];
  const float* vp       = (const float*)d_in[18];
  float* out = (float*)d_out;
  float* ws = (float*)d_ws;  // 137 KB scratch: Wf, Wz, U, Gpre

  // pre-kernel: all b-independent weight algebra, once (same stream -> ordered)
  fold_kernel<<<259, 128, 0, stream>>>(W1, W2, Wp, W_ih, W_emb, b_emb, b_ih,
                                       b1, b2, ws);

  const int shmem = SM_FLOATS * 4;
  static_assert(SM_FLOATS * 4 <= 160 * 1024, "LDS overlay too big");
  hipFuncSetAttribute((const void*)decoder_kernel,
                      hipFuncAttributeMaxDynamicSharedMemorySize, shmem);
  decoder_kernel<<<NB, 1024, shmem, stream>>>(
      instance, solution, Z, IH, last_hh, W_hh, b_hh, W_a, v_a, Wp, vp, ws,
      out);
}

// Round 13
// 290.427 us; speedup vs baseline: 1.2915x; 1.0310x over previous
//
#include <hip/hip_runtime.h>
#include <math.h>

#define NB 256
#define NS 64
#define NH 128
#define NZ 128
#define NSTEPS 63
#define HP 144   // HALL row pitch (padh layout within each row)
#define PP 132   // preA/preP/atth(ptrh)/ctx row pitch
#define SP 68    // scores row pitch

// LDS float-offsets (total 39812 floats = 155.5 KiB)
#define OFF_PREA 0       // 8448: exp(2*preA) post-chain; WN lives here during chain
#define OFF_PREP 8448    // 8448 -> [0,16896): exp(2*preP)
#define OFF_WN   0       // 512*33 = 16896: gate-n weight slices (chain only)
#define OFF_HALL 16896   // 9216 -> [16896,26112)
#define OFF_ATTH 26112   // 8448: IH stage, then exp(2*atth) / exp(2*ptrh)
#define OFF_SCOR 34560   // 4352 -> [34560,38912)
#define OFF_U    38912   // 384
#define OFF_VA   39296   // 128
#define OFF_VPV  39424   // 128
#define OFF_REFX 39552   // 64
#define OFF_REFY 39616   // 64
#define OFF_SOL  39680   // 64 (int)
#define OFF_RANK 39744   // 64 (int)
#define OFF_SVA  39808   // 1: sum(v_a)
#define OFF_SVP  39809   // 1: sum(vp)
#define SM_FLOATS 39812
// startup temps inside SCOR region (dead before SCOR first written):
#define OFF_GPRE 34560   // 1152
#define OFF_BHH  35712   // 384

// workspace (d_ws) float offsets
#define WS_WF   0        // 16384: (W1[:H]@W2)@Wp[H:]
#define WS_WZ   16384    // 16384: (W1[H:H+ZD]@W2)@Wp[H:]
#define WS_U    32768    // 384:   U0,U1,U2const
#define WS_GPRE 33152    // 1152:  [W_emb;b_emb]@W_ih^T (+b_ih)
#define WS_FLOATS 34304

// +4 pad per 32-float chunk (r1-validated conflict fix for HALL rows)
__device__ __forceinline__ int padh(int i) { return i + ((i >> 5) << 2); }

// fast tanh / sigmoid (validated r1/r4-r12)
__device__ __forceinline__ float ftanh(float x) {
  float e = __expf(2.0f * x);
  return 1.0f - 2.0f * __builtin_amdgcn_rcpf(e + 1.0f);
}
__device__ __forceinline__ float fsigm(float x) {
  return __builtin_amdgcn_rcpf(1.0f + __expf(-x));
}

// pin 8 scalar floats into VGPRs: asm results can't be rematerialized-by-reload
#define PIN8(a, i)                                                          \
  asm volatile("" : "+v"((a)[(i)]), "+v"((a)[(i) + 1]), "+v"((a)[(i) + 2]), \
                    "+v"((a)[(i) + 3]), "+v"((a)[(i) + 4]),                 \
                    "+v"((a)[(i) + 5]), "+v"((a)[(i) + 6]),                 \
                    "+v"((a)[(i) + 7]))

// ---- pre-kernel: ALL b-independent weight algebra, computed ONCE ----
__global__ __launch_bounds__(128, 1) void fold_kernel(
    const float* __restrict__ W1, const float* __restrict__ W2,
    const float* __restrict__ Wp, const float* __restrict__ W_ih,
    const float* __restrict__ W_emb, const float* __restrict__ b_emb,
    const float* __restrict__ b_ih, const float* __restrict__ b1,
    const float* __restrict__ b2, float* __restrict__ ws) {
  __shared__ float srow[NH];
  __shared__ float amS[256];
  const int g = blockIdx.x;
  const int o = threadIdx.x;  // 0..127
  if (g < 256) {
    const int r = (g < 128) ? g : (NH + (g - 128));
    const float* w1r = W1 + r * 256;
    float acc = 0.f;
#pragma unroll 16
    for (int m = 0; m < 256; ++m) acc += w1r[m] * W2[m * NH + o];
    srow[o] = acc;
    __syncthreads();
    float wf = 0.f;
#pragma unroll 16
    for (int j = 0; j < NH; ++j) wf += srow[j] * Wp[(NH + j) * NH + o];
    if (g < 128) ws[WS_WF + g * NH + o] = wf;
    else         ws[WS_WZ + (g - 128) * NH + o] = wf;
    if (g >= 1 && g <= 3) {
      const int row = (g - 1) * NH + o;
      const float* wi = W_ih + row * NH;
      float g0 = 0.f, g1 = 0.f, g2 = 0.f;
#pragma unroll 8
      for (int k4 = 0; k4 < 32; ++k4) {
        float4 w = *(const float4*)(wi + 4 * k4);
        float4 e0 = *(const float4*)(W_emb + 4 * k4);
        float4 e1 = *(const float4*)(W_emb + NH + 4 * k4);
        float4 eb = *(const float4*)(b_emb + 4 * k4);
        g0 += w.x * e0.x + w.y * e0.y + w.z * e0.z + w.w * e0.w;
        g1 += w.x * e1.x + w.y * e1.y + w.z * e1.z + w.w * e1.w;
        g2 += w.x * eb.x + w.y * eb.y + w.z * eb.z + w.w * eb.w;
      }
      ws[WS_GPRE + row] = g0;
      ws[WS_GPRE + 384 + row] = g1;
      ws[WS_GPRE + 768 + row] = g2 + b_ih[row];
    }
  } else {
    // U-chain for channel c: am[256] -> v[128] -> U[128]
    const int c = g - 256;  // 0:emb_x 1:emb_y 2:bias
    const float* ev = (c == 0) ? W_emb : (c == 1) ? (W_emb + NH) : b_emb;
#pragma unroll
    for (int half = 0; half < 2; ++half) {
      const int m = o + 128 * half;
      float a = 0.f;
#pragma unroll 8
      for (int k = 0; k < NH; ++k) a += ev[k] * W1[(2 * NH + k) * 256 + m];
      amS[m] = (c == 2) ? (a + b1[m]) : a;
    }
    __syncthreads();
    float vv = (c == 2) ? b2[o] : 0.f;
#pragma unroll 16
    for (int m = 0; m < 256; ++m) vv += amS[m] * W2[m * NH + o];
    srow[o] = vv;
    __syncthreads();
    float U = 0.f;
#pragma unroll 16
    for (int j = 0; j < NH; ++j) U += srow[j] * Wp[(NH + j) * NH + o];
    ws[WS_U + c * NH + o] = U;
  }
}

// r12 structure + exponential-product score form: producers store E=exp(2x);
// score = sum_v - 2*sum_o v_o * rcp(Ea*Eh + 1) — 3 VALU/element vs tadd's 5.
// (tanh(a+h) = 1 - 2/(e^{2a}e^{2h}+1), exact identity; overflow->rcp->0->
// tanh->1 is the correct limit.)
__global__ __launch_bounds__(1024, 1) void decoder_kernel(
    const float* __restrict__ instance, const int* __restrict__ solution,
    const float* __restrict__ Z, const float* __restrict__ IH,
    const float* __restrict__ last_hh, const float* __restrict__ W_hh,
    const float* __restrict__ b_hh, const float* __restrict__ W_a,
    const float* __restrict__ v_a, const float* __restrict__ Wp,
    const float* __restrict__ vp, const float* __restrict__ ws,
    float* __restrict__ out) {
  extern __shared__ float sm[];
  int* soli = (int*)(sm + OFF_SOL);
  int* ranki = (int*)(sm + OFF_RANK);
  const int b = blockIdx.x;
  const int t = threadIdx.x;
  const float* ihb = IH + b * NS * NH;

  // ---------- thread-role constants ----------
  const int oc = t >> 3, qc = t & 7;        // chain: 128 outs x 8 k-chunks of 16
  const int oq = (t & 31) * 4, jg = t >> 5; // B/D/P: o-quad x 32 j-strips (i<2)
  const int jj = t >> 4, sq = t & 15;       // C/G/H: 64 rows x 16 lanes (i<4)

  // ================= startup (single phase) =================
  if (t < NS) {
    int sv = solution[b * NS + t];
    soli[t] = sv;
    ranki[sv] = t;
    sm[OFF_REFX + t] = instance[(b * NS + sv) * 2 + 0];
    sm[OFF_REFY + t] = instance[(b * NS + sv) * 2 + 1];
  }
  if (t < NH) {
    sm[OFF_VA + t] = v_a[t];
    sm[OFF_VPV + t] = vp[t];
    sm[OFF_HALL + padh(t)] = last_hh[b * NH + t];  // h0
  }
  // sum(v_a) by wave 0, sum(vp) by wave 1 (global reads; no barrier dep)
  if (t < 128) {
    const float* vsrc = (t < 64) ? v_a : vp;
    int u = t & 63;
    float s2 = vsrc[u] + vsrc[u + 64];
#pragma unroll
    for (int off = 32; off > 0; off >>= 1) s2 += __shfl_xor(s2, off);
    if (u == 0) sm[(t < 64) ? OFF_SVA : OFF_SVP] = s2;
  }
  if (t < 384) sm[OFF_BHH + t] = b_hh[t];
  // Gpre + U0/U1 from precomputed workspace
  for (int i = t; i < 1152; i += 1024) sm[OFF_GPRE + i] = ws[WS_GPRE + i];
  if (t < 256) sm[OFF_U + t] = ws[WS_U + t];
  // U2 = U2const + Z[b] @ Wz  (the only per-b piece of the MLP affine)
  {
    const float* zb = Z + b * NZ;
    float acc = 0.f;
#pragma unroll 4
    for (int u = 0; u < 16; ++u) {
      int k = 16 * qc + u;
      acc += zb[k] * ws[WS_WZ + k * NH + oc];
    }
    acc += __shfl_xor(acc, 1); acc += __shfl_xor(acc, 2); acc += __shfl_xor(acc, 4);
    if (qc == 0) sm[OFF_U + 2 * NH + oc] = ws[WS_U + 2 * NH + oc] + acc;
  }
  // gate-n weights -> LDS slices (512 slices of 32, pitch 33)
  if (t < 512) {
    const int o4 = t >> 2, q4 = t & 3;
    const float* wnp = W_hh + (2 * NH + o4) * NH + 32 * q4;
#pragma unroll
    for (int u4 = 0; u4 < 8; ++u4) {
      float4 w = *(const float4*)(wnp + 4 * u4);
      sm[OFF_WN + t * 33 + 4 * u4 + 0] = w.x;
      sm[OFF_WN + t * 33 + 4 * u4 + 1] = w.y;
      sm[OFF_WN + t * 33 + 4 * u4 + 2] = w.z;
      sm[OFF_WN + t * 33 + 4 * u4 + 3] = w.w;
    }
  }
  if (t == 0) out[b * NS] = (float)soli[0];
  __syncthreads();

  // ========== h-chain: the ONLY serial recurrence (63 iters, 1 barrier each).
  {
    float whr[16], whz[16];
    {
      const float* br = W_hh + oc * NH + 16 * qc;
      const float* bz = W_hh + (NH + oc) * NH + 16 * qc;
#pragma unroll
      for (int u4 = 0; u4 < 4; ++u4) {
        float4 r4 = *(const float4*)(br + 4 * u4);
        float4 z4 = *(const float4*)(bz + 4 * u4);
        whr[4 * u4 + 0] = r4.x; whr[4 * u4 + 1] = r4.y;
        whr[4 * u4 + 2] = r4.z; whr[4 * u4 + 3] = r4.w;
        whz[4 * u4 + 0] = z4.x; whz[4 * u4 + 1] = z4.y;
        whz[4 * u4 + 2] = z4.z; whz[4 * u4 + 3] = z4.w;
      }
    }
    PIN8(whr, 0); PIN8(whr, 8);
    PIN8(whz, 0); PIN8(whz, 8);
    const float* wn = sm + OFF_WN + (oc * 4 + (qc >> 1)) * 33 + (qc & 1) * 16;
    const int hoffc = padh(16 * qc);
    // hoist loop-invariant LDS scalars
    const float bhr = sm[OFF_BHH + oc];
    const float bhz = sm[OFF_BHH + NH + oc];
    const float bhn = sm[OFF_BHH + 2 * NH + oc];
    const float gr0 = sm[OFF_GPRE + oc];
    const float gr1 = sm[OFF_GPRE + 384 + oc];
    const float gr2 = sm[OFF_GPRE + 768 + oc];
    const float gz0 = sm[OFF_GPRE + NH + oc];
    const float gz1 = sm[OFF_GPRE + 384 + NH + oc];
    const float gz2 = sm[OFF_GPRE + 768 + NH + oc];
    const float gn0 = sm[OFF_GPRE + 2 * NH + oc];
    const float gn1 = sm[OFF_GPRE + 384 + 2 * NH + oc];
    const float gn2 = sm[OFF_GPRE + 768 + 2 * NH + oc];
#pragma unroll 1
    for (int j = 1; j <= NSTEPS; ++j) {
      float ar = 0.f, az = 0.f, an = 0.f;
      const float* hp = sm + OFF_HALL + (j - 1) * HP + hoffc;
#pragma unroll
      for (int u = 0; u < 4; ++u) {
        float4 hv = *(const float4*)(hp + 4 * u);
        ar += hv.x * whr[4 * u] + hv.y * whr[4 * u + 1] +
              hv.z * whr[4 * u + 2] + hv.w * whr[4 * u + 3];
        az += hv.x * whz[4 * u] + hv.y * whz[4 * u + 1] +
              hv.z * whz[4 * u + 2] + hv.w * whz[4 * u + 3];
        an += hv.x * wn[4 * u] + hv.y * wn[4 * u + 1] +
              hv.z * wn[4 * u + 2] + hv.w * wn[4 * u + 3];
      }
      ar += __shfl_xor(ar, 1); ar += __shfl_xor(ar, 2); ar += __shfl_xor(ar, 4);
      az += __shfl_xor(az, 1); az += __shfl_xor(az, 2); az += __shfl_xor(az, 4);
      an += __shfl_xor(an, 1); an += __shfl_xor(an, 2); an += __shfl_xor(an, 4);
      if (qc == 0) {
        float r0 = sm[OFF_REFX + (j - 1)], r1 = sm[OFF_REFY + (j - 1)];
        float gir = r0 * gr0 + r1 * gr1 + gr2;
        float giz = r0 * gz0 + r1 * gz1 + gz2;
        float gin = r0 * gn0 + r1 * gn1 + gn2;
        float r = fsigm(gir + ar + bhr);
        float z = fsigm(giz + az + bhz);
        float n = ftanh(gin + r * (an + bhn));
        float hold = sm[OFF_HALL + (j - 1) * HP + padh(oc)];
        sm[OFF_HALL + j * HP + padh(oc)] = (1.f - z) * n + z * hold;
      }
      __syncthreads();
    }
  }

  // ========== stage IH into ATTH region ==========
  for (int i = 4 * t; i < NS * NH; i += 4096)
    *(float4*)(sm + OFF_ATTH + i) = *(const float4*)(ihb + i);
  __syncthreads();
  // ========== preA/preP -> stored as exp(2*.) (overwrites dead WN region) ====
  {
    const int jx = t & 127, sg = t >> 7;  // sg 0..7, wave-uniform
    float accA[8], accP[8];
#pragma unroll
    for (int si = 0; si < 8; ++si) { accA[si] = 0.f; accP[si] = 0.f; }
#pragma unroll 2
    for (int k4 = 0; k4 < 32; ++k4) {
      const int k = 4 * k4;
      float wa0 = W_a[(k + 0) * NH + jx];
      float wa1 = W_a[(k + 1) * NH + jx];
      float wa2 = W_a[(k + 2) * NH + jx];
      float wa3 = W_a[(k + 3) * NH + jx];
      float wp0 = Wp[(k + 0) * NH + jx];
      float wp1 = Wp[(k + 1) * NH + jx];
      float wp2 = Wp[(k + 2) * NH + jx];
      float wp3 = Wp[(k + 3) * NH + jx];
#pragma unroll
      for (int si = 0; si < 8; ++si) {
        float4 ih = *(const float4*)(sm + OFF_ATTH + (sg * 8 + si) * NH + k);
        accA[si] += ih.x * wa0 + ih.y * wa1 + ih.z * wa2 + ih.w * wa3;
        accP[si] += ih.x * wp0 + ih.y * wp1 + ih.z * wp2 + ih.w * wp3;
      }
    }
#pragma unroll
    for (int si = 0; si < 8; ++si) {
      sm[OFF_PREA + (sg * 8 + si) * PP + jx] = __expf(2.f * accA[si]);
      sm[OFF_PREP + (sg * 8 + si) * PP + jx] = __expf(2.f * accP[si]);
    }
  }
  __syncthreads();

  // ========== B: atthB[j] = h_j @ W_a[H:] -> stored as exp(2*.) ==========
  {
    float4 acc[2];
    acc[0] = (float4){0.f, 0.f, 0.f, 0.f};
    acc[1] = (float4){0.f, 0.f, 0.f, 0.f};
    const float* wbase = W_a + NH * NH + oq;
#pragma unroll 4
    for (int k4 = 0; k4 < 32; ++k4) {
      int k = 4 * k4;
      int hoff = k + 4 * (k4 >> 3);  // padh offset
      float4 w0 = *(const float4*)(wbase + (k + 0) * NH);
      float4 w1 = *(const float4*)(wbase + (k + 1) * NH);
      float4 w2 = *(const float4*)(wbase + (k + 2) * NH);
      float4 w3 = *(const float4*)(wbase + (k + 3) * NH);
#pragma unroll
      for (int i = 0; i < 2; ++i) {
        float4 hv = *(const float4*)(sm + OFF_HALL + (jg + 32 * i) * HP + hoff);
        acc[i].x += hv.x * w0.x + hv.y * w1.x + hv.z * w2.x + hv.w * w3.x;
        acc[i].y += hv.x * w0.y + hv.y * w1.y + hv.z * w2.y + hv.w * w3.y;
        acc[i].z += hv.x * w0.z + hv.y * w1.z + hv.z * w2.z + hv.w * w3.z;
        acc[i].w += hv.x * w0.w + hv.y * w1.w + hv.z * w2.w + hv.w * w3.w;
      }
    }
#pragma unroll
    for (int i = 0; i < 2; ++i) {
      float4 tv;
      tv.x = __expf(2.f * acc[i].x); tv.y = __expf(2.f * acc[i].y);
      tv.z = __expf(2.f * acc[i].z); tv.w = __expf(2.f * acc[i].w);
      *(float4*)(sm + OFF_ATTH + (jg + 32 * i) * PP + oq) = tv;
    }
  }
  __syncthreads();

  // ========== C: scores = sva - 2*sum v*rcp(Ea*Eh+1), FUSED softmax ==========
  {
    const float sva = sm[OFF_SVA];
    const float* ah = sm + OFF_ATTH + jj * PP;
    float accv[4] = {0.f, 0.f, 0.f, 0.f};
#pragma unroll 2
    for (int k4 = 0; k4 < 32; ++k4) {
      float4 h = *(const float4*)(ah + 4 * k4);
      float4 v = *(const float4*)(sm + OFF_VA + 4 * k4);
#pragma unroll
      for (int i = 0; i < 4; ++i) {
        float4 a = *(const float4*)(sm + OFF_PREA + (sq + 16 * i) * PP + 4 * k4);
        accv[i] += v.x * __builtin_amdgcn_rcpf(fmaf(a.x, h.x, 1.f)) +
                   v.y * __builtin_amdgcn_rcpf(fmaf(a.y, h.y, 1.f)) +
                   v.z * __builtin_amdgcn_rcpf(fmaf(a.z, h.z, 1.f)) +
                   v.w * __builtin_amdgcn_rcpf(fmaf(a.w, h.w, 1.f));
      }
    }
#pragma unroll
    for (int i = 0; i < 4; ++i) accv[i] = sva - 2.f * accv[i];
    float m = fmaxf(fmaxf(accv[0], accv[1]), fmaxf(accv[2], accv[3]));
    m = fmaxf(m, __shfl_xor(m, 1));
    m = fmaxf(m, __shfl_xor(m, 2));
    m = fmaxf(m, __shfl_xor(m, 4));
    m = fmaxf(m, __shfl_xor(m, 8));
    float p0 = __expf(accv[0] - m), p1 = __expf(accv[1] - m);
    float p2 = __expf(accv[2] - m), p3 = __expf(accv[3] - m);
    float ssum = (p0 + p1) + (p2 + p3);
    ssum += __shfl_xor(ssum, 1); ssum += __shfl_xor(ssum, 2);
    ssum += __shfl_xor(ssum, 4); ssum += __shfl_xor(ssum, 8);
    sm[OFF_SCOR + jj * SP + sq + 0]  = p0 / ssum;
    sm[OFF_SCOR + jj * SP + sq + 16] = p1 / ssum;
    sm[OFF_SCOR + jj * SP + sq + 32] = p2 / ssum;
    sm[OFF_SCOR + jj * SP + sq + 48] = p3 / ssum;
  }
  __syncthreads();

  // ========== D: ctx[j] = attn[j] @ IH (into preA buffer; IH from L2) ==========
  {
    float4 acc[2];
    acc[0] = (float4){0.f, 0.f, 0.f, 0.f};
    acc[1] = (float4){0.f, 0.f, 0.f, 0.f};
    const float* ibase = ihb + oq;
#pragma unroll 4
    for (int s4 = 0; s4 < 16; ++s4) {
      int s = 4 * s4;
      float4 x0 = *(const float4*)(ibase + (s + 0) * NH);
      float4 x1 = *(const float4*)(ibase + (s + 1) * NH);
      float4 x2 = *(const float4*)(ibase + (s + 2) * NH);
      float4 x3 = *(const float4*)(ibase + (s + 3) * NH);
#pragma unroll
      for (int i = 0; i < 2; ++i) {
        const float* at = sm + OFF_SCOR + (jg + 32 * i) * SP + s;
        float a0 = at[0], a1 = at[1], a2 = at[2], a3 = at[3];
        acc[i].x += a0 * x0.x + a1 * x1.x + a2 * x2.x + a3 * x3.x;
        acc[i].y += a0 * x0.y + a1 * x1.y + a2 * x2.y + a3 * x3.y;
        acc[i].z += a0 * x0.z + a1 * x1.z + a2 * x2.z + a3 * x3.z;
        acc[i].w += a0 * x0.w + a1 * x1.w + a2 * x2.w + a3 * x3.w;
      }
    }
#pragma unroll
    for (int i = 0; i < 2; ++i)
      *(float4*)(sm + OFF_PREA + (jg + 32 * i) * PP + oq) = acc[i];
  }
  __syncthreads();

  // ========== P: ptrh[j] = ctx[j] @ Wf + affine -> stored as exp(2*.) ========
  {
    float4 acc[2];
    acc[0] = (float4){0.f, 0.f, 0.f, 0.f};
    acc[1] = (float4){0.f, 0.f, 0.f, 0.f};
    const float* wfb = ws + WS_WF + oq;
#pragma unroll 4
    for (int k4 = 0; k4 < 32; ++k4) {
      int k = 4 * k4;
      float4 w0 = *(const float4*)(wfb + (k + 0) * NH);
      float4 w1 = *(const float4*)(wfb + (k + 1) * NH);
      float4 w2 = *(const float4*)(wfb + (k + 2) * NH);
      float4 w3 = *(const float4*)(wfb + (k + 3) * NH);
#pragma unroll
      for (int i = 0; i < 2; ++i) {
        float4 cv = *(const float4*)(sm + OFF_PREA + (jg + 32 * i) * PP + k);
        acc[i].x += cv.x * w0.x + cv.y * w1.x + cv.z * w2.x + cv.w * w3.x;
        acc[i].y += cv.x * w0.y + cv.y * w1.y + cv.z * w2.y + cv.w * w3.y;
        acc[i].z += cv.x * w0.z + cv.y * w1.z + cv.z * w2.z + cv.w * w3.z;
        acc[i].w += cv.x * w0.w + cv.y * w1.w + cv.z * w2.w + cv.w * w3.w;
      }
    }
    float4 u0 = *(const float4*)(sm + OFF_U + oq);
    float4 u1 = *(const float4*)(sm + OFF_U + NH + oq);
    float4 u2 = *(const float4*)(sm + OFF_U + 2 * NH + oq);
#pragma unroll
    for (int i = 0; i < 2; ++i) {
      int j = jg + 32 * i;
      int jm = (j > 0) ? (j - 1) : 0;  // row 0 unused; clamp avoids OOB
      float rx = sm[OFF_REFX + jm], ry = sm[OFF_REFY + jm];
      float4 r;
      r.x = __expf(2.f * (acc[i].x + rx * u0.x + ry * u1.x + u2.x));
      r.y = __expf(2.f * (acc[i].y + rx * u0.y + ry * u1.y + u2.y));
      r.z = __expf(2.f * (acc[i].z + rx * u0.z + ry * u1.z + u2.z));
      r.w = __expf(2.f * (acc[i].w + rx * u0.w + ry * u1.w + u2.w));
      *(float4*)(sm + OFF_ATTH + j * PP + oq) = r;
    }
  }
  __syncthreads();

  // ========== G: glogits = svp - 2*sum vp*rcp(Ep*Eh+1) -> SCOR ==========
  {
    const float svp = sm[OFF_SVP];
    const float* ph = sm + OFF_ATTH + jj * PP;
    float accv[4] = {0.f, 0.f, 0.f, 0.f};
#pragma unroll 2
    for (int k4 = 0; k4 < 32; ++k4) {
      float4 h = *(const float4*)(ph + 4 * k4);
      float4 v = *(const float4*)(sm + OFF_VPV + 4 * k4);
#pragma unroll
      for (int i = 0; i < 4; ++i) {
        float4 a = *(const float4*)(sm + OFF_PREP + (sq + 16 * i) * PP + 4 * k4);
        accv[i] += v.x * __builtin_amdgcn_rcpf(fmaf(a.x, h.x, 1.f)) +
                   v.y * __builtin_amdgcn_rcpf(fmaf(a.y, h.y, 1.f)) +
                   v.z * __builtin_amdgcn_rcpf(fmaf(a.z, h.z, 1.f)) +
                   v.w * __builtin_amdgcn_rcpf(fmaf(a.w, h.w, 1.f));
      }
    }
#pragma unroll
    for (int i = 0; i < 4; ++i)
      sm[OFF_SCOR + jj * SP + sq + 16 * i] = svp - 2.f * accv[i];
  }
  __syncthreads();

  // ========== H: masked log-softmax + argmax (first-index tie) + outputs =====
  {
    float ml[4];
    float m = -INFINITY;
    int mi = 127;
#pragma unroll
    for (int i = 0; i < 4; ++i) {
      int s = sq + 16 * i;
      float lg = sm[OFF_SCOR + jj * SP + s];
      ml[i] = (ranki[s] >= jj) ? lg : -INFINITY;  // mask excludes sol[0..j-1]
      if (ml[i] > m) { m = ml[i]; mi = s; }       // ascending s: earliest on tie
    }
#pragma unroll
    for (int off = 1; off <= 8; off <<= 1) {
      float om = __shfl_xor(m, off);
      int oi = __shfl_xor(mi, off);
      if (om > m || (om == m && oi < mi)) { m = om; mi = oi; }
    }
    float ssum = 0.f;
#pragma unroll
    for (int i = 0; i < 4; ++i) ssum += __expf(ml[i] - m);
    ssum += __shfl_xor(ssum, 1); ssum += __shfl_xor(ssum, 2);
    ssum += __shfl_xor(ssum, 4); ssum += __shfl_xor(ssum, 8);
    if (sq == 0 && jj >= 1) {
      out[b * NS + jj] = (float)mi;
      float pv = sm[OFF_SCOR + jj * SP + soli[jj]];  // sol[j] unmasked at step j
      out[NB * NS + b * NSTEPS + (jj - 1)] = pv - m - __logf(ssum);
    }
  }
}

extern "C" void kernel_launch(void* const* d_in, const int* in_sizes, int n_in,
                              void* d_out, int out_size, void* d_ws,
                              size_t ws_size, hipStream_t stream) {
  (void)in_sizes; (void)n_in; (void)out_size; (void)ws_size;
  const float* instance = (const float*)d_in[0];
  const int*   solution = (const int*)d_in[1];
  const float* Z        = (const float*)d_in[2];
  const float* IH       = (const float*)d_in[3];
  const float* last_hh  = (const float*)d_in[4];
  const float* W_emb    = (const float*)d_in[5];
  const float* b_emb    = (const float*)d_in[6];
  const float* W_ih     = (const float*)d_in[7];
  const float* W_hh     = (const float*)d_in[8];
  const float* b_ih     = (const float*)d_in[9];
  const float* b_hh     = (const float*)d_in[10];
  const float* W_a      = (const float*)d_in[11];
  const float* v_a      = (const float*)d_in[12];
  const float* W1       = (const float*)d_in[13];
  const float* b1       = (const float*)d_in[14];
  const float* W2       = (const float*)d_in[15];
  const float* b2       = (const float*)d_in[16];
  const float* Wp       = (const float*)d_in[17];
  const float* vp       = (const float*)d_in[18];
  float* out = (float*)d_out;
  float* ws = (float*)d_ws;  // 137 KB scratch: Wf, Wz, U, Gpre

  // pre-kernel: all b-independent weight algebra, once (same stream -> ordered)
  fold_kernel<<<259, 128, 0, stream>>>(W1, W2, Wp, W_ih, W_emb, b_emb, b_ih,
                                       b1, b2, ws);

  const int shmem = SM_FLOATS * 4;
  static_assert(SM_FLOATS * 4 <= 160 * 1024, "LDS overlay too big");
  hipFuncSetAttribute((const void*)decoder_kernel,
                      hipFuncAttributeMaxDynamicSharedMemorySize, shmem);
  decoder_kernel<<<NB, 1024, shmem, stream>>>(
      instance, solution, Z, IH, last_hh, W_hh, b_hh, W_a, v_a, Wp, vp, ws,
      out);
}